// Round 1
// baseline (4702.584 us; speedup 1.0000x reference)
//
#include <hip/hip_runtime.h>

#define HW 65536
#define NC 12
#define NF 64
#define NT 8

typedef float2 c32;

__device__ __forceinline__ float ssign(int p) {
    // (-1)^(x+y), x = p&255, y = p>>8
    return ((p ^ (p >> 8)) & 1) ? -1.0f : 1.0f;
}

// ===================== 256-point radix-2 DIT FFT in LDS =====================
// X: 256 complex in LDS (natural order result), tw: 128 forward twiddles
// j: lane role 0..63 (each does 2 butterflies/stage), conjf: +1 fwd, -1 inv
__device__ __forceinline__ void fft256_stages(c32* X, const c32* tw, int j, float conjf) {
    #pragma unroll
    for (int s = 1; s <= 8; ++s) {
        const int half = 1 << (s - 1);
        #pragma unroll
        for (int b = 0; b < 2; ++b) {
            int idx = j + (b << 6);
            int grp = idx >> (s - 1);
            int pos = idx & (half - 1);
            int i0 = (grp << s) + pos;
            int i1 = i0 + half;
            c32 w = tw[pos << (8 - s)];
            float wy = conjf * w.y;
            c32 a = X[i0], cc = X[i1];
            c32 t = make_float2(w.x * cc.x - wy * cc.y, w.x * cc.y + wy * cc.x);
            X[i0] = make_float2(a.x + t.x, a.y + t.y);
            X[i1] = make_float2(a.x - t.x, a.y - t.y);
        }
        __syncthreads();
    }
}

__device__ __forceinline__ void build_tw(c32* tw, int tid) {
    if (tid < 128) {
        float a = -3.14159265358979323846f * (float)tid * (1.0f / 128.0f);
        float sv, cv;
        sincosf(a, &sv, &cv);
        tw[tid] = make_float2(cv, sv);
    }
}

// grid: nrows/4 blocks, 256 threads. buf = [rows][256] contiguous complex rows.
__global__ __launch_bounds__(256) void fft_rows(c32* __restrict__ buf, float conjf) {
    __shared__ c32 lds[4][256];
    __shared__ c32 tw[128];
    int tid = threadIdx.x;
    build_tw(tw, tid);
    int wid = tid >> 6, j = tid & 63;
    c32* rp = buf + (size_t)(blockIdx.x * 4 + wid) * 256;
    c32* X = lds[wid];
    #pragma unroll
    for (int e = 0; e < 4; ++e) {
        int n = (e << 6) + j;
        X[__brev((unsigned)n) >> 24] = rp[n];
    }
    __syncthreads();
    fft256_stages(X, tw, j, conjf);
    #pragma unroll
    for (int e = 0; e < 4; ++e) {
        int n = (e << 6) + j;
        rp[n] = X[n];
    }
}

// grid: dim3(64, nimg), 256 threads. Each block: 4 columns of one 256x256 image.
__global__ __launch_bounds__(256) void fft_cols(c32* __restrict__ buf, float conjf) {
    __shared__ c32 lds[4][257];   // +1 pad to soften bit-reverse bank conflicts
    __shared__ c32 tw[128];
    int tid = threadIdx.x;
    build_tw(tw, tid);
    c32* ip = buf + (size_t)blockIdx.y * HW;
    int x0 = blockIdx.x * 4;
    int cl = tid & 3, yb = tid >> 2;
    #pragma unroll
    for (int e = 0; e < 4; ++e) {
        int y = yb + (e << 6);
        lds[cl][__brev((unsigned)y) >> 24] = ip[y * 256 + x0 + cl];
    }
    __syncthreads();
    int col = tid >> 6, j = tid & 63;
    fft256_stages(&lds[col][0], tw, j, conjf);
    #pragma unroll
    for (int e = 0; e < 4; ++e) {
        int y = yb + (e << 6);
        ip[y * 256 + x0 + cl] = lds[cl][y];
    }
}

// ===================== pointwise kernels =====================
// P1: tmp = S * pred  (prep for unnormalized inverse FFT)
__global__ __launch_bounds__(256) void k_pre(const c32* __restrict__ pred, c32* __restrict__ tmp) {
    int i = blockIdx.x * 256 + threadIdx.x;
    int p = i & (HW - 1);
    float s = ssign(p);
    c32 v = pred[i];
    tmp[i] = make_float2(s * v.x, s * v.y);
}

// P2: eta = sum_c tmp_c * conj(sense_c) * S/256
__global__ __launch_bounds__(256) void k_combine_eta0(const c32* __restrict__ tmp,
        const c32* __restrict__ sense, c32* __restrict__ eta) {
    int p = blockIdx.x * 256 + threadIdx.x;
    float ax = 0.f, ay = 0.f;
    for (int c = 0; c < NC; ++c) {
        c32 t = tmp[c * HW + p], s = sense[c * HW + p];
        ax += t.x * s.x + t.y * s.y;   // t * conj(s)
        ay += t.y * s.x - t.x * s.y;
    }
    float sc = ssign(p) * (1.0f / 256.0f);
    eta[p] = make_float2(ax * sc, ay * sc);
}

// P0: base = ksp - where(mask, (pred-ksp)*dcw, 0)
__global__ __launch_bounds__(256) void k_base(const c32* __restrict__ ksp,
        const c32* __restrict__ pred, const int* __restrict__ mask,
        const float* __restrict__ dcw, c32* __restrict__ base) {
    int i = blockIdx.x * 256 + threadIdx.x;
    int p = i & (HW - 1);
    c32 k = ksp[i];
    c32 o = k;
    if (mask[p]) {
        float w = dcw[0];
        c32 pr = pred[i];
        o.x -= (pr.x - k.x) * w;
        o.y -= (pr.y - k.y) * w;
    }
    base[i] = o;
}

// P3: Fk = S * (eta * sense)   (prep for forward FFT, G = FFT2u(Fk))
__global__ __launch_bounds__(256) void k_expand(const c32* __restrict__ eta,
        const c32* __restrict__ sense, c32* __restrict__ Fk) {
    int i = blockIdx.x * 256 + threadIdx.x;
    int p = i & (HW - 1);
    float s = ssign(p);
    c32 e = eta[p], sn = sense[i];
    Fk[i] = make_float2(s * (e.x * sn.x - e.y * sn.y), s * (e.x * sn.y + e.y * sn.x));
}

// P4: tmp = mask ? (G/256 - S*ksp) : 0   (S-folded masked residual, pre-iFFT)
__global__ __launch_bounds__(256) void k_resid(const c32* __restrict__ Fk,
        const c32* __restrict__ ksp, const int* __restrict__ mask, c32* __restrict__ tmp) {
    int i = blockIdx.x * 256 + threadIdx.x;
    int p = i & (HW - 1);
    if (!mask[p]) { tmp[i] = make_float2(0.f, 0.f); return; }
    float s = ssign(p);
    c32 g = Fk[i], k = ksp[i];
    tmp[i] = make_float2(g.x * (1.0f / 256.0f) - s * k.x,
                         g.y * (1.0f / 256.0f) - s * k.y);
}

// P5: grad = sum_c tmp_c * conj(sense_c) * S/256 ; g = [eta.re, eta.im, grad.re, grad.im]
__global__ __launch_bounds__(256) void k_grad_g(const c32* __restrict__ tmp,
        const c32* __restrict__ sense, const c32* __restrict__ eta, float* __restrict__ g) {
    int p = blockIdx.x * 256 + threadIdx.x;
    float ax = 0.f, ay = 0.f;
    for (int c = 0; c < NC; ++c) {
        c32 t = tmp[c * HW + p], s = sense[c * HW + p];
        ax += t.x * s.x + t.y * s.y;
        ay += t.y * s.x - t.x * s.y;
    }
    float sc = ssign(p) * (1.0f / 256.0f);
    c32 e = eta[p];
    g[0 * HW + p] = e.x;           // inv_s2 = 1
    g[1 * HW + p] = e.y;
    g[2 * HW + p] = ax * sc;
    g[3 * HW + p] = ay * sc;
}

// P6: out[t] = base - S*G/256
__global__ __launch_bounds__(256) void k_out(const c32* __restrict__ base,
        const c32* __restrict__ Fk, c32* __restrict__ outp) {
    int i = blockIdx.x * 256 + threadIdx.x;
    int p = i & (HW - 1);
    float sc = ssign(p) * (1.0f / 256.0f);
    c32 g = Fk[i], b = base[i];
    outp[i] = make_float2(b.x - sc * g.x, b.y - sc * g.y);
}

// ===================== convolutions =====================
// conv1: 4->64, 5x5, pad 2, relu. grid (256, 16), block 256. 4 co per thread.
__global__ __launch_bounds__(256) void conv1_relu(const float* __restrict__ g,
        const float* __restrict__ w, const float* __restrict__ b, float* __restrict__ out) {
    int x = threadIdx.x, y = blockIdx.x, co0 = blockIdx.y << 2;
    float a0 = b[co0], a1 = b[co0 + 1], a2 = b[co0 + 2], a3 = b[co0 + 3];
    #pragma unroll
    for (int ci = 0; ci < 4; ++ci) {
        #pragma unroll
        for (int ky = 0; ky < 5; ++ky) {
            int yy = y + ky - 2;
            if ((unsigned)yy >= 256u) continue;
            const float* row = g + ci * HW + yy * 256;
            const float* wr = w + co0 * 100 + ci * 25 + ky * 5;
            #pragma unroll
            for (int kx = 0; kx < 5; ++kx) {
                int xx = x + kx - 2;
                if ((unsigned)xx >= 256u) continue;
                float v = row[xx];
                a0 += v * wr[kx];
                a1 += v * wr[100 + kx];
                a2 += v * wr[200 + kx];
                a3 += v * wr[300 + kx];
            }
        }
    }
    int o = y * 256 + x;
    out[(co0 + 0) * HW + o] = fmaxf(a0, 0.f);
    out[(co0 + 1) * HW + o] = fmaxf(a1, 0.f);
    out[(co0 + 2) * HW + o] = fmaxf(a2, 0.f);
    out[(co0 + 3) * HW + o] = fmaxf(a3, 0.f);
}

// conv2: 64->64, 3x3 dilation 2, pad 2, relu. grid (256, 16), block 256.
__global__ __launch_bounds__(256) void conv2_relu(const float* __restrict__ hin,
        const float* __restrict__ w, const float* __restrict__ b, float* __restrict__ out) {
    int x = threadIdx.x, y = blockIdx.x, co0 = blockIdx.y << 2;
    float a0 = b[co0], a1 = b[co0 + 1], a2 = b[co0 + 2], a3 = b[co0 + 3];
    for (int ci = 0; ci < 64; ++ci) {
        const float* wc = w + co0 * 576 + ci * 9;
        #pragma unroll
        for (int ky = 0; ky < 3; ++ky) {
            int yy = y + (ky - 1) * 2;
            if ((unsigned)yy >= 256u) continue;
            const float* row = hin + ci * HW + yy * 256;
            #pragma unroll
            for (int kx = 0; kx < 3; ++kx) {
                int xx = x + (kx - 1) * 2;
                if ((unsigned)xx >= 256u) continue;
                float v = row[xx];
                int wi = ky * 3 + kx;
                a0 += v * wc[wi];
                a1 += v * wc[576 + wi];
                a2 += v * wc[1152 + wi];
                a3 += v * wc[1728 + wi];
            }
        }
    }
    int o = y * 256 + x;
    out[(co0 + 0) * HW + o] = fmaxf(a0, 0.f);
    out[(co0 + 1) * HW + o] = fmaxf(a1, 0.f);
    out[(co0 + 2) * HW + o] = fmaxf(a2, 0.f);
    out[(co0 + 3) * HW + o] = fmaxf(a3, 0.f);
}

// fused ConvGRU (1x1 convs + gates). grid (256, 16), block 256. 4 co per thread.
__global__ __launch_bounds__(256) void gru_fused(const float* __restrict__ xin,
        const float* __restrict__ h, const float* __restrict__ ihw, const float* __restrict__ ihb,
        const float* __restrict__ hhw, const float* __restrict__ hhb, float* __restrict__ hout) {
    int x = threadIdx.x, y = blockIdx.x, co0 = blockIdx.y << 2;
    int p = y * 256 + x;
    float ir[4] = {0, 0, 0, 0}, iz[4] = {0, 0, 0, 0}, in_[4] = {0, 0, 0, 0};
    float hr[4] = {0, 0, 0, 0}, hz[4] = {0, 0, 0, 0}, hn[4] = {0, 0, 0, 0};
    #pragma unroll 4
    for (int ci = 0; ci < 64; ++ci) {
        float xv = xin[ci * HW + p];
        float hv = h[ci * HW + p];
        #pragma unroll
        for (int q = 0; q < 4; ++q) {
            int co = co0 + q;
            ir[q] += xv * ihw[co * 64 + ci];
            iz[q] += xv * ihw[(64 + co) * 64 + ci];
            in_[q] += xv * ihw[(128 + co) * 64 + ci];
            hr[q] += hv * hhw[co * 64 + ci];
            hz[q] += hv * hhw[(64 + co) * 64 + ci];
            hn[q] += hv * hhw[(128 + co) * 64 + ci];
        }
    }
    #pragma unroll
    for (int q = 0; q < 4; ++q) {
        int co = co0 + q;
        float r = ir[q] + ihb[co] + hr[q] + hhb[co];
        r = 1.0f / (1.0f + expf(-r));
        float z = iz[q] + ihb[64 + co] + hz[q] + hhb[64 + co];
        z = 1.0f / (1.0f + expf(-z));
        float n = tanhf(in_[q] + ihb[128 + co] + r * (hn[q] + hhb[128 + co]));
        float hcur = h[co * HW + p];
        hout[co * HW + p] = (1.0f - z) * n + z * hcur;
    }
}

// final conv 64->2, 3x3, pad 1, no bias; eta += (d0, d1). grid 256, block 256.
__global__ __launch_bounds__(256) void final_conv_eta(const float* __restrict__ h2,
        const float* __restrict__ w, c32* __restrict__ eta) {
    int x = threadIdx.x, y = blockIdx.x;
    float a0 = 0.f, a1 = 0.f;
    for (int ci = 0; ci < 64; ++ci) {
        const float* wc = w + ci * 9;
        #pragma unroll
        for (int ky = 0; ky < 3; ++ky) {
            int yy = y + ky - 1;
            if ((unsigned)yy >= 256u) continue;
            const float* row = h2 + ci * HW + yy * 256;
            #pragma unroll
            for (int kx = 0; kx < 3; ++kx) {
                int xx = x + kx - 1;
                if ((unsigned)xx >= 256u) continue;
                float v = row[xx];
                a0 += v * wc[ky * 3 + kx];
                a1 += v * wc[576 + ky * 3 + kx];
            }
        }
    }
    int p = y * 256 + x;
    c32 e = eta[p];
    eta[p] = make_float2(e.x + a0, e.y + a1);
}

// ===================== host orchestration =====================
extern "C" void kernel_launch(void* const* d_in, const int* in_sizes, int n_in,
                              void* d_out, int out_size, void* d_ws, size_t ws_size,
                              hipStream_t stream) {
    const c32* pred   = (const c32*)d_in[0];
    const c32* ksp    = (const c32*)d_in[1];
    const c32* sense  = (const c32*)d_in[2];
    const int* mask   = (const int*)d_in[3];
    const float* c1w  = (const float*)d_in[4];
    const float* c1b  = (const float*)d_in[5];
    const float* g1iw = (const float*)d_in[6];
    const float* g1ib = (const float*)d_in[7];
    const float* g1hw = (const float*)d_in[8];
    const float* g1hb = (const float*)d_in[9];
    const float* c2w  = (const float*)d_in[10];
    const float* c2b  = (const float*)d_in[11];
    const float* g2iw = (const float*)d_in[12];
    const float* g2ib = (const float*)d_in[13];
    const float* g2hw = (const float*)d_in[14];
    const float* g2hb = (const float*)d_in[15];
    const float* fw   = (const float*)d_in[16];
    const float* dcw  = (const float*)d_in[17];

    float* w0 = (float*)d_ws;
    c32* base = (c32*)w0;                  // NC*HW complex
    c32* Fk   = base + NC * HW;            // NC*HW complex (cached forward FFT)
    c32* tmp  = Fk + NC * HW;              // NC*HW complex (FFT scratch)
    c32* eta  = tmp + NC * HW;             // HW complex
    float* g  = (float*)(eta + HW);        // 4*HW
    float* x1 = g + 4 * HW;                // NF*HW (also reused as x2)
    float* h1a = x1 + NF * HW;
    float* h1b = h1a + NF * HW;
    float* h2a = h1b + NF * HW;
    float* h2b = h2a + NF * HW;

    (void)hipMemsetAsync(h1a, 0, (size_t)NF * HW * 4, stream);
    (void)hipMemsetAsync(h2a, 0, (size_t)NF * HW * 4, stream);

    dim3 B(256);
    const int gCHW = NC * HW / 256;   // 3072
    const int gHW  = HW / 256;        // 256
    const int gROW = NC * 256 / 4;    // 768
    dim3 gCOL(64, NC);
    dim3 gCONV(256, 16);

    // eta0 = sum_c ifft2c(pred_c) * conj(sense_c)
    k_pre<<<gCHW, B, 0, stream>>>(pred, tmp);
    fft_rows<<<gROW, B, 0, stream>>>(tmp, -1.0f);   // inverse: conj twiddles
    fft_cols<<<gCOL, B, 0, stream>>>(tmp, -1.0f);
    k_combine_eta0<<<gHW, B, 0, stream>>>(tmp, sense, eta);

    k_base<<<gCHW, B, 0, stream>>>(ksp, pred, mask, dcw, base);

    // F_0 (unnormalized, S-folded): G = FFT2u(S*(eta*sense))
    k_expand<<<gCHW, B, 0, stream>>>(eta, sense, Fk);
    fft_rows<<<gROW, B, 0, stream>>>(Fk, 1.0f);     // forward
    fft_cols<<<gCOL, B, 0, stream>>>(Fk, 1.0f);

    float* h1c = h1a; float* h1n = h1b;
    float* h2c = h2a; float* h2n = h2b;
    c32* outp = (c32*)d_out;

    for (int t = 0; t < NT; ++t) {
        // gradient from cached F_{t-1}
        k_resid<<<gCHW, B, 0, stream>>>(Fk, ksp, mask, tmp);
        fft_rows<<<gROW, B, 0, stream>>>(tmp, -1.0f);
        fft_cols<<<gCOL, B, 0, stream>>>(tmp, -1.0f);
        k_grad_g<<<gHW, B, 0, stream>>>(tmp, sense, eta, g);

        // network
        conv1_relu<<<gCONV, B, 0, stream>>>(g, c1w, c1b, x1);
        gru_fused<<<gCONV, B, 0, stream>>>(x1, h1c, g1iw, g1ib, g1hw, g1hb, h1n);
        { float* s = h1c; h1c = h1n; h1n = s; }
        conv2_relu<<<gCONV, B, 0, stream>>>(h1c, c2w, c2b, x1);  // x1 reused as x2
        gru_fused<<<gCONV, B, 0, stream>>>(x1, h2c, g2iw, g2ib, g2hw, g2hb, h2n);
        { float* s = h2c; h2c = h2n; h2n = s; }
        final_conv_eta<<<256, B, 0, stream>>>(h2c, fw, eta);

        // F_t for this step's output (and next step's gradient)
        k_expand<<<gCHW, B, 0, stream>>>(eta, sense, Fk);
        fft_rows<<<gROW, B, 0, stream>>>(Fk, 1.0f);
        fft_cols<<<gCOL, B, 0, stream>>>(Fk, 1.0f);
        k_out<<<gCHW, B, 0, stream>>>(base, Fk, outp + (size_t)t * NC * HW);
    }
}

// Round 3
// 3883.184 us; speedup vs baseline: 1.2110x; 1.2110x over previous
//
#include <hip/hip_runtime.h>

#define HW 65536
#define NC 12
#define NF 64
#define NT 8

typedef float2 c32;

__device__ __forceinline__ float ssign(int p) {
    // (-1)^(x+y), x = p&255, y = p>>8
    return ((p ^ (p >> 8)) & 1) ? -1.0f : 1.0f;
}

// ===================== 256-point radix-2 DIT FFT in LDS =====================
__device__ __forceinline__ void fft256_stages(c32* X, const c32* tw, int j, float conjf) {
    #pragma unroll
    for (int s = 1; s <= 8; ++s) {
        const int half = 1 << (s - 1);
        #pragma unroll
        for (int b = 0; b < 2; ++b) {
            int idx = j + (b << 6);
            int grp = idx >> (s - 1);
            int pos = idx & (half - 1);
            int i0 = (grp << s) + pos;
            int i1 = i0 + half;
            c32 w = tw[pos << (8 - s)];
            float wy = conjf * w.y;
            c32 a = X[i0], cc = X[i1];
            c32 t = make_float2(w.x * cc.x - wy * cc.y, w.x * cc.y + wy * cc.x);
            X[i0] = make_float2(a.x + t.x, a.y + t.y);
            X[i1] = make_float2(a.x - t.x, a.y - t.y);
        }
        __syncthreads();
    }
}

__device__ __forceinline__ void build_tw(c32* tw, int tid) {
    if (tid < 128) {
        float a = -3.14159265358979323846f * (float)tid * (1.0f / 128.0f);
        float sv, cv;
        sincosf(a, &sv, &cv);
        tw[tid] = make_float2(cv, sv);
    }
}

// grid: nrows/4 blocks, 256 threads. buf = [rows][256] contiguous complex rows.
__global__ __launch_bounds__(256) void fft_rows(c32* __restrict__ buf, float conjf) {
    __shared__ c32 lds[4][256];
    __shared__ c32 tw[128];
    int tid = threadIdx.x;
    build_tw(tw, tid);
    int wid = tid >> 6, j = tid & 63;
    c32* rp = buf + (size_t)(blockIdx.x * 4 + wid) * 256;
    c32* X = lds[wid];
    #pragma unroll
    for (int e = 0; e < 4; ++e) {
        int n = (e << 6) + j;
        X[__brev((unsigned)n) >> 24] = rp[n];
    }
    __syncthreads();
    fft256_stages(X, tw, j, conjf);
    #pragma unroll
    for (int e = 0; e < 4; ++e) {
        int n = (e << 6) + j;
        rp[n] = X[n];
    }
}

// grid: dim3(64, nimg), 256 threads. Each block: 4 columns of one 256x256 image.
__global__ __launch_bounds__(256) void fft_cols(c32* __restrict__ buf, float conjf) {
    __shared__ c32 lds[4][257];   // +1 pad to soften bit-reverse bank conflicts
    __shared__ c32 tw[128];
    int tid = threadIdx.x;
    build_tw(tw, tid);
    c32* ip = buf + (size_t)blockIdx.y * HW;
    int x0 = blockIdx.x * 4;
    int cl = tid & 3, yb = tid >> 2;
    #pragma unroll
    for (int e = 0; e < 4; ++e) {
        int y = yb + (e << 6);
        lds[cl][__brev((unsigned)y) >> 24] = ip[y * 256 + x0 + cl];
    }
    __syncthreads();
    int col = tid >> 6, j = tid & 63;
    fft256_stages(&lds[col][0], tw, j, conjf);
    #pragma unroll
    for (int e = 0; e < 4; ++e) {
        int y = yb + (e << 6);
        ip[y * 256 + x0 + cl] = lds[cl][y];
    }
}

// ===================== pointwise kernels =====================
// P1: tmp = S * pred  (prep for unnormalized inverse FFT)
__global__ __launch_bounds__(256) void k_pre(const c32* __restrict__ pred, c32* __restrict__ tmp) {
    int i = blockIdx.x * 256 + threadIdx.x;
    int p = i & (HW - 1);
    float s = ssign(p);
    c32 v = pred[i];
    tmp[i] = make_float2(s * v.x, s * v.y);
}

// P2: eta = sum_c tmp_c * conj(sense_c) * S/256
__global__ __launch_bounds__(256) void k_combine_eta0(const c32* __restrict__ tmp,
        const c32* __restrict__ sense, c32* __restrict__ eta) {
    int p = blockIdx.x * 256 + threadIdx.x;
    float ax = 0.f, ay = 0.f;
    for (int c = 0; c < NC; ++c) {
        c32 t = tmp[c * HW + p], s = sense[c * HW + p];
        ax += t.x * s.x + t.y * s.y;   // t * conj(s)
        ay += t.y * s.x - t.x * s.y;
    }
    float sc = ssign(p) * (1.0f / 256.0f);
    eta[p] = make_float2(ax * sc, ay * sc);
}

// P0: base = ksp - where(mask, (pred-ksp)*dcw, 0)
__global__ __launch_bounds__(256) void k_base(const c32* __restrict__ ksp,
        const c32* __restrict__ pred, const int* __restrict__ mask,
        const float* __restrict__ dcw, c32* __restrict__ base) {
    int i = blockIdx.x * 256 + threadIdx.x;
    int p = i & (HW - 1);
    c32 k = ksp[i];
    c32 o = k;
    if (mask[p]) {
        float w = dcw[0];
        c32 pr = pred[i];
        o.x -= (pr.x - k.x) * w;
        o.y -= (pr.y - k.y) * w;
    }
    base[i] = o;
}

// P3: Fk = S * (eta * sense)   (prep for forward FFT, G = FFT2u(Fk))
__global__ __launch_bounds__(256) void k_expand(const c32* __restrict__ eta,
        const c32* __restrict__ sense, c32* __restrict__ Fk) {
    int i = blockIdx.x * 256 + threadIdx.x;
    int p = i & (HW - 1);
    float s = ssign(p);
    c32 e = eta[p], sn = sense[i];
    Fk[i] = make_float2(s * (e.x * sn.x - e.y * sn.y), s * (e.x * sn.y + e.y * sn.x));
}

// P4: tmp = mask ? (G/256 - S*ksp) : 0   (S-folded masked residual, pre-iFFT)
__global__ __launch_bounds__(256) void k_resid(const c32* __restrict__ Fk,
        const c32* __restrict__ ksp, const int* __restrict__ mask, c32* __restrict__ tmp) {
    int i = blockIdx.x * 256 + threadIdx.x;
    int p = i & (HW - 1);
    if (!mask[p]) { tmp[i] = make_float2(0.f, 0.f); return; }
    float s = ssign(p);
    c32 g = Fk[i], k = ksp[i];
    tmp[i] = make_float2(g.x * (1.0f / 256.0f) - s * k.x,
                         g.y * (1.0f / 256.0f) - s * k.y);
}

// P5: grad = sum_c tmp_c * conj(sense_c) * S/256 ; g = [eta.re, eta.im, grad.re, grad.im]
__global__ __launch_bounds__(256) void k_grad_g(const c32* __restrict__ tmp,
        const c32* __restrict__ sense, const c32* __restrict__ eta, float* __restrict__ g) {
    int p = blockIdx.x * 256 + threadIdx.x;
    float ax = 0.f, ay = 0.f;
    for (int c = 0; c < NC; ++c) {
        c32 t = tmp[c * HW + p], s = sense[c * HW + p];
        ax += t.x * s.x + t.y * s.y;
        ay += t.y * s.x - t.x * s.y;
    }
    float sc = ssign(p) * (1.0f / 256.0f);
    c32 e = eta[p];
    g[0 * HW + p] = e.x;           // inv_s2 = 1
    g[1 * HW + p] = e.y;
    g[2 * HW + p] = ax * sc;
    g[3 * HW + p] = ay * sc;
}

// P6: out[t] = base - S*G/256
__global__ __launch_bounds__(256) void k_out(const c32* __restrict__ base,
        const c32* __restrict__ Fk, c32* __restrict__ outp) {
    int i = blockIdx.x * 256 + threadIdx.x;
    int p = i & (HW - 1);
    float sc = ssign(p) * (1.0f / 256.0f);
    c32 g = Fk[i], b = base[i];
    outp[i] = make_float2(b.x - sc * g.x, b.y - sc * g.y);
}

// ===================== convolutions =====================
// conv1: 4->64, 5x5, pad 2, relu. grid (256, 4), block 256. 16 co per thread.
__global__ __launch_bounds__(256) void conv1_relu(const float* __restrict__ g,
        const float* __restrict__ w, const float* __restrict__ b, float* __restrict__ out) {
    int x = threadIdx.x, y = blockIdx.x, co0 = blockIdx.y << 4;
    float acc[16];
    #pragma unroll
    for (int q = 0; q < 16; ++q) acc[q] = b[co0 + q];
    #pragma unroll
    for (int ci = 0; ci < 4; ++ci) {
        float v[25];
        #pragma unroll
        for (int ky = 0; ky < 5; ++ky) {
            int yy = y + ky - 2;
            bool yok = (unsigned)yy < 256u;
            const float* row = g + ci * HW + yy * 256;
            #pragma unroll
            for (int kx = 0; kx < 5; ++kx) {
                int xx = x + kx - 2;
                v[ky * 5 + kx] = (yok && (unsigned)xx < 256u) ? row[xx] : 0.f;
            }
        }
        const float* wb = w + co0 * 100 + ci * 25;
        #pragma unroll
        for (int q = 0; q < 16; ++q) {
            const float* wq = wb + q * 100;
            #pragma unroll
            for (int t = 0; t < 25; ++t) acc[q] += v[t] * wq[t];
        }
    }
    int o = y * 256 + x;
    #pragma unroll
    for (int q = 0; q < 16; ++q) out[(co0 + q) * HW + o] = fmaxf(acc[q], 0.f);
}

// conv2: 64->64, 3x3 dilation 2, pad 2, relu. grid (256, 4), block 256. 16 co per thread.
__global__ __launch_bounds__(256) void conv2_relu(const float* __restrict__ hin,
        const float* __restrict__ w, const float* __restrict__ b, float* __restrict__ out) {
    int x = threadIdx.x, y = blockIdx.x, co0 = blockIdx.y << 4;
    float acc[16];
    #pragma unroll
    for (int q = 0; q < 16; ++q) acc[q] = b[co0 + q];
    for (int ci = 0; ci < 64; ++ci) {
        float v[9];
        #pragma unroll
        for (int ky = 0; ky < 3; ++ky) {
            int yy = y + (ky - 1) * 2;
            bool yok = (unsigned)yy < 256u;
            const float* row = hin + ci * HW + yy * 256;
            #pragma unroll
            for (int kx = 0; kx < 3; ++kx) {
                int xx = x + (kx - 1) * 2;
                v[ky * 3 + kx] = (yok && (unsigned)xx < 256u) ? row[xx] : 0.f;
            }
        }
        const float* wb = w + co0 * 576 + ci * 9;
        #pragma unroll
        for (int q = 0; q < 16; ++q) {
            const float* wq = wb + q * 576;
            #pragma unroll
            for (int t = 0; t < 9; ++t) acc[q] += v[t] * wq[t];
        }
    }
    int o = y * 256 + x;
    #pragma unroll
    for (int q = 0; q < 16; ++q) out[(co0 + q) * HW + o] = fmaxf(acc[q], 0.f);
}

// fused ConvGRU (1x1 convs + gates). grid (256, 8), block 256. 8 co per thread.
__global__ __launch_bounds__(256) void gru_fused(const float* __restrict__ xin,
        const float* __restrict__ h, const float* __restrict__ ihw, const float* __restrict__ ihb,
        const float* __restrict__ hhw, const float* __restrict__ hhb, float* __restrict__ hout) {
    int x = threadIdx.x, y = blockIdx.x, co0 = blockIdx.y << 3;
    int p = y * 256 + x;
    float ir[8] = {}, iz[8] = {}, in_[8] = {};
    float hr[8] = {}, hz[8] = {}, hn[8] = {};
    #pragma unroll 4
    for (int ci = 0; ci < 64; ++ci) {
        float xv = xin[ci * HW + p];
        float hv = h[ci * HW + p];
        #pragma unroll
        for (int q = 0; q < 8; ++q) {
            int co = co0 + q;
            ir[q] += xv * ihw[co * 64 + ci];
            iz[q] += xv * ihw[(64 + co) * 64 + ci];
            in_[q] += xv * ihw[(128 + co) * 64 + ci];
            hr[q] += hv * hhw[co * 64 + ci];
            hz[q] += hv * hhw[(64 + co) * 64 + ci];
            hn[q] += hv * hhw[(128 + co) * 64 + ci];
        }
    }
    #pragma unroll
    for (int q = 0; q < 8; ++q) {
        int co = co0 + q;
        float r = ir[q] + ihb[co] + hr[q] + hhb[co];
        r = 1.0f / (1.0f + expf(-r));
        float z = iz[q] + ihb[64 + co] + hz[q] + hhb[64 + co];
        z = 1.0f / (1.0f + expf(-z));
        float n = tanhf(in_[q] + ihb[128 + co] + r * (hn[q] + hhb[128 + co]));
        float hcur = h[co * HW + p];
        hout[co * HW + p] = (1.0f - z) * n + z * hcur;
    }
}

// final conv 64->2, 3x3, pad 1, no bias; eta += (d0, d1). grid 256, block 256.
__global__ __launch_bounds__(256) void final_conv_eta(const float* __restrict__ h2,
        const float* __restrict__ w, c32* __restrict__ eta) {
    int x = threadIdx.x, y = blockIdx.x;
    float a0 = 0.f, a1 = 0.f;
    for (int ci = 0; ci < 64; ++ci) {
        float v[9];
        #pragma unroll
        for (int ky = 0; ky < 3; ++ky) {
            int yy = y + ky - 1;
            bool yok = (unsigned)yy < 256u;
            const float* row = h2 + ci * HW + yy * 256;
            #pragma unroll
            for (int kx = 0; kx < 3; ++kx) {
                int xx = x + kx - 1;
                v[ky * 3 + kx] = (yok && (unsigned)xx < 256u) ? row[xx] : 0.f;
            }
        }
        const float* wc = w + ci * 9;
        #pragma unroll
        for (int t = 0; t < 9; ++t) {
            a0 += v[t] * wc[t];
            a1 += v[t] * wc[576 + t];
        }
    }
    int p = y * 256 + x;
    c32 e = eta[p];
    eta[p] = make_float2(e.x + a0, e.y + a1);
}

// ===================== host orchestration =====================
extern "C" void kernel_launch(void* const* d_in, const int* in_sizes, int n_in,
                              void* d_out, int out_size, void* d_ws, size_t ws_size,
                              hipStream_t stream) {
    const c32* pred   = (const c32*)d_in[0];
    const c32* ksp    = (const c32*)d_in[1];
    const c32* sense  = (const c32*)d_in[2];
    const int* mask   = (const int*)d_in[3];
    const float* c1w  = (const float*)d_in[4];
    const float* c1b  = (const float*)d_in[5];
    const float* g1iw = (const float*)d_in[6];
    const float* g1ib = (const float*)d_in[7];
    const float* g1hw = (const float*)d_in[8];
    const float* g1hb = (const float*)d_in[9];
    const float* c2w  = (const float*)d_in[10];
    const float* c2b  = (const float*)d_in[11];
    const float* g2iw = (const float*)d_in[12];
    const float* g2ib = (const float*)d_in[13];
    const float* g2hw = (const float*)d_in[14];
    const float* g2hb = (const float*)d_in[15];
    const float* fw   = (const float*)d_in[16];
    const float* dcw  = (const float*)d_in[17];

    float* w0 = (float*)d_ws;
    c32* base = (c32*)w0;                  // NC*HW complex
    c32* Fk   = base + NC * HW;            // NC*HW complex (cached forward FFT)
    c32* tmp  = Fk + NC * HW;              // NC*HW complex (FFT scratch)
    c32* eta  = tmp + NC * HW;             // HW complex
    float* g  = (float*)(eta + HW);        // 4*HW
    float* x1 = g + 4 * HW;                // NF*HW (also reused as x2)
    float* h1a = x1 + NF * HW;
    float* h1b = h1a + NF * HW;
    float* h2a = h1b + NF * HW;
    float* h2b = h2a + NF * HW;

    (void)hipMemsetAsync(h1a, 0, (size_t)NF * HW * 4, stream);
    (void)hipMemsetAsync(h2a, 0, (size_t)NF * HW * 4, stream);

    dim3 B(256);
    const int gCHW = NC * HW / 256;   // 3072
    const int gHW  = HW / 256;        // 256
    const int gROW = NC * 256 / 4;    // 768
    dim3 gCOL(64, NC);
    dim3 gC16(256, 4);
    dim3 gGRU(256, 8);

    // eta0 = sum_c ifft2c(pred_c) * conj(sense_c)
    k_pre<<<gCHW, B, 0, stream>>>(pred, tmp);
    fft_rows<<<gROW, B, 0, stream>>>(tmp, -1.0f);   // inverse: conj twiddles
    fft_cols<<<gCOL, B, 0, stream>>>(tmp, -1.0f);
    k_combine_eta0<<<gHW, B, 0, stream>>>(tmp, sense, eta);

    k_base<<<gCHW, B, 0, stream>>>(ksp, pred, mask, dcw, base);

    // F_0 (unnormalized, S-folded): G = FFT2u(S*(eta*sense))
    k_expand<<<gCHW, B, 0, stream>>>(eta, sense, Fk);
    fft_rows<<<gROW, B, 0, stream>>>(Fk, 1.0f);     // forward
    fft_cols<<<gCOL, B, 0, stream>>>(Fk, 1.0f);

    float* h1c = h1a; float* h1n = h1b;
    float* h2c = h2a; float* h2n = h2b;
    c32* outp = (c32*)d_out;

    for (int t = 0; t < NT; ++t) {
        // gradient from cached F_{t-1}
        k_resid<<<gCHW, B, 0, stream>>>(Fk, ksp, mask, tmp);
        fft_rows<<<gROW, B, 0, stream>>>(tmp, -1.0f);
        fft_cols<<<gCOL, B, 0, stream>>>(tmp, -1.0f);
        k_grad_g<<<gHW, B, 0, stream>>>(tmp, sense, eta, g);

        // network
        conv1_relu<<<gC16, B, 0, stream>>>(g, c1w, c1b, x1);
        gru_fused<<<gGRU, B, 0, stream>>>(x1, h1c, g1iw, g1ib, g1hw, g1hb, h1n);
        { float* s = h1c; h1c = h1n; h1n = s; }
        conv2_relu<<<gC16, B, 0, stream>>>(h1c, c2w, c2b, x1);  // x1 reused as x2
        gru_fused<<<gGRU, B, 0, stream>>>(x1, h2c, g2iw, g2ib, g2hw, g2hb, h2n);
        { float* s = h2c; h2c = h2n; h2n = s; }
        final_conv_eta<<<256, B, 0, stream>>>(h2c, fw, eta);

        // F_t for this step's output (and next step's gradient)
        k_expand<<<gCHW, B, 0, stream>>>(eta, sense, Fk);
        fft_rows<<<gROW, B, 0, stream>>>(Fk, 1.0f);
        fft_cols<<<gCOL, B, 0, stream>>>(Fk, 1.0f);
        k_out<<<gCHW, B, 0, stream>>>(base, Fk, outp + (size_t)t * NC * HW);
    }
}

// Round 4
// 3770.160 us; speedup vs baseline: 1.2473x; 1.0300x over previous
//
#include <hip/hip_runtime.h>

#define HW 65536
#define NC 12
#define NF 64
#define NT 8

typedef float2 c32;

__device__ __forceinline__ float ssign(int p) {
    // (-1)^(x+y), x = p&255, y = p>>8
    return ((p ^ (p >> 8)) & 1) ? -1.0f : 1.0f;
}

// ===================== 256-point radix-2 DIT FFT in LDS =====================
__device__ __forceinline__ void fft256_stages(c32* X, const c32* tw, int j, float conjf) {
    #pragma unroll
    for (int s = 1; s <= 8; ++s) {
        const int half = 1 << (s - 1);
        #pragma unroll
        for (int b = 0; b < 2; ++b) {
            int idx = j + (b << 6);
            int grp = idx >> (s - 1);
            int pos = idx & (half - 1);
            int i0 = (grp << s) + pos;
            int i1 = i0 + half;
            c32 w = tw[pos << (8 - s)];
            float wy = conjf * w.y;
            c32 a = X[i0], cc = X[i1];
            c32 t = make_float2(w.x * cc.x - wy * cc.y, w.x * cc.y + wy * cc.x);
            X[i0] = make_float2(a.x + t.x, a.y + t.y);
            X[i1] = make_float2(a.x - t.x, a.y - t.y);
        }
        __syncthreads();
    }
}

__device__ __forceinline__ void build_tw(c32* tw, int tid) {
    if (tid < 128) {
        float a = -3.14159265358979323846f * (float)tid * (1.0f / 128.0f);
        float sv, cv;
        sincosf(a, &sv, &cv);
        tw[tid] = make_float2(cv, sv);
    }
}

// grid: nrows/4 blocks, 256 threads. buf = [rows][256] contiguous complex rows.
__global__ __launch_bounds__(256) void fft_rows(c32* __restrict__ buf, float conjf) {
    __shared__ c32 lds[4][256];
    __shared__ c32 tw[128];
    int tid = threadIdx.x;
    build_tw(tw, tid);
    int wid = tid >> 6, j = tid & 63;
    c32* rp = buf + (size_t)(blockIdx.x * 4 + wid) * 256;
    c32* X = lds[wid];
    #pragma unroll
    for (int e = 0; e < 4; ++e) {
        int n = (e << 6) + j;
        X[__brev((unsigned)n) >> 24] = rp[n];
    }
    __syncthreads();
    fft256_stages(X, tw, j, conjf);
    #pragma unroll
    for (int e = 0; e < 4; ++e) {
        int n = (e << 6) + j;
        rp[n] = X[n];
    }
}

// grid: dim3(64, nimg), 256 threads. Each block: 4 columns of one 256x256 image.
__global__ __launch_bounds__(256) void fft_cols(c32* __restrict__ buf, float conjf) {
    __shared__ c32 lds[4][257];   // +1 pad to soften bit-reverse bank conflicts
    __shared__ c32 tw[128];
    int tid = threadIdx.x;
    build_tw(tw, tid);
    c32* ip = buf + (size_t)blockIdx.y * HW;
    int x0 = blockIdx.x * 4;
    int cl = tid & 3, yb = tid >> 2;
    #pragma unroll
    for (int e = 0; e < 4; ++e) {
        int y = yb + (e << 6);
        lds[cl][__brev((unsigned)y) >> 24] = ip[y * 256 + x0 + cl];
    }
    __syncthreads();
    int col = tid >> 6, j = tid & 63;
    fft256_stages(&lds[col][0], tw, j, conjf);
    #pragma unroll
    for (int e = 0; e < 4; ++e) {
        int y = yb + (e << 6);
        ip[y * 256 + x0 + cl] = lds[cl][y];
    }
}

// ===================== pointwise kernels =====================
// P1: tmp = S * pred  (prep for unnormalized inverse FFT)
__global__ __launch_bounds__(256) void k_pre(const c32* __restrict__ pred, c32* __restrict__ tmp) {
    int i = blockIdx.x * 256 + threadIdx.x;
    int p = i & (HW - 1);
    float s = ssign(p);
    c32 v = pred[i];
    tmp[i] = make_float2(s * v.x, s * v.y);
}

// P2: eta = sum_c tmp_c * conj(sense_c) * S/256
__global__ __launch_bounds__(256) void k_combine_eta0(const c32* __restrict__ tmp,
        const c32* __restrict__ sense, c32* __restrict__ eta) {
    int p = blockIdx.x * 256 + threadIdx.x;
    float ax = 0.f, ay = 0.f;
    for (int c = 0; c < NC; ++c) {
        c32 t = tmp[c * HW + p], s = sense[c * HW + p];
        ax += t.x * s.x + t.y * s.y;   // t * conj(s)
        ay += t.y * s.x - t.x * s.y;
    }
    float sc = ssign(p) * (1.0f / 256.0f);
    eta[p] = make_float2(ax * sc, ay * sc);
}

// P0: base = ksp - where(mask, (pred-ksp)*dcw, 0)
__global__ __launch_bounds__(256) void k_base(const c32* __restrict__ ksp,
        const c32* __restrict__ pred, const int* __restrict__ mask,
        const float* __restrict__ dcw, c32* __restrict__ base) {
    int i = blockIdx.x * 256 + threadIdx.x;
    int p = i & (HW - 1);
    c32 k = ksp[i];
    c32 o = k;
    if (mask[p]) {
        float w = dcw[0];
        c32 pr = pred[i];
        o.x -= (pr.x - k.x) * w;
        o.y -= (pr.y - k.y) * w;
    }
    base[i] = o;
}

// P3: Fk = S * (eta * sense)   (prep for forward FFT, G = FFT2u(Fk))
__global__ __launch_bounds__(256) void k_expand(const c32* __restrict__ eta,
        const c32* __restrict__ sense, c32* __restrict__ Fk) {
    int i = blockIdx.x * 256 + threadIdx.x;
    int p = i & (HW - 1);
    float s = ssign(p);
    c32 e = eta[p], sn = sense[i];
    Fk[i] = make_float2(s * (e.x * sn.x - e.y * sn.y), s * (e.x * sn.y + e.y * sn.x));
}

// P4: tmp = mask ? (G/256 - S*ksp) : 0   (S-folded masked residual, pre-iFFT)
__global__ __launch_bounds__(256) void k_resid(const c32* __restrict__ Fk,
        const c32* __restrict__ ksp, const int* __restrict__ mask, c32* __restrict__ tmp) {
    int i = blockIdx.x * 256 + threadIdx.x;
    int p = i & (HW - 1);
    if (!mask[p]) { tmp[i] = make_float2(0.f, 0.f); return; }
    float s = ssign(p);
    c32 g = Fk[i], k = ksp[i];
    tmp[i] = make_float2(g.x * (1.0f / 256.0f) - s * k.x,
                         g.y * (1.0f / 256.0f) - s * k.y);
}

// P5: grad = sum_c tmp_c * conj(sense_c) * S/256 ; g = [eta.re, eta.im, grad.re, grad.im]
__global__ __launch_bounds__(256) void k_grad_g(const c32* __restrict__ tmp,
        const c32* __restrict__ sense, const c32* __restrict__ eta, float* __restrict__ g) {
    int p = blockIdx.x * 256 + threadIdx.x;
    float ax = 0.f, ay = 0.f;
    for (int c = 0; c < NC; ++c) {
        c32 t = tmp[c * HW + p], s = sense[c * HW + p];
        ax += t.x * s.x + t.y * s.y;
        ay += t.y * s.x - t.x * s.y;
    }
    float sc = ssign(p) * (1.0f / 256.0f);
    c32 e = eta[p];
    g[0 * HW + p] = e.x;           // inv_s2 = 1
    g[1 * HW + p] = e.y;
    g[2 * HW + p] = ax * sc;
    g[3 * HW + p] = ay * sc;
}

// P6: out[t] = base - S*G/256
__global__ __launch_bounds__(256) void k_out(const c32* __restrict__ base,
        const c32* __restrict__ Fk, c32* __restrict__ outp) {
    int i = blockIdx.x * 256 + threadIdx.x;
    int p = i & (HW - 1);
    float sc = ssign(p) * (1.0f / 256.0f);
    c32 g = Fk[i], b = base[i];
    outp[i] = make_float2(b.x - sc * g.x, b.y - sc * g.y);
}

// ===================== convolutions =====================
// conv1: 4->64, 5x5, pad 2, relu. grid (256, 4), block 256. 16 co per thread.
// __launch_bounds__(256,4): cap at 128 VGPR so the 16 accumulators + 25 taps
// live in real VGPRs (default codegen parked them in AGPRs -> accvgpr churn).
__global__ __launch_bounds__(256, 4) void conv1_relu(const float* __restrict__ g,
        const float* __restrict__ w, const float* __restrict__ b, float* __restrict__ out) {
    int x = threadIdx.x, y = blockIdx.x, co0 = blockIdx.y << 4;
    float acc[16];
    #pragma unroll
    for (int q = 0; q < 16; ++q) acc[q] = b[co0 + q];
    #pragma unroll
    for (int ci = 0; ci < 4; ++ci) {
        float v[25];
        #pragma unroll
        for (int ky = 0; ky < 5; ++ky) {
            int yy = y + ky - 2;
            bool yok = (unsigned)yy < 256u;
            const float* row = g + ci * HW + yy * 256;
            #pragma unroll
            for (int kx = 0; kx < 5; ++kx) {
                int xx = x + kx - 2;
                v[ky * 5 + kx] = (yok && (unsigned)xx < 256u) ? row[xx] : 0.f;
            }
        }
        const float* wb = w + co0 * 100 + ci * 25;
        #pragma unroll
        for (int q = 0; q < 16; ++q) {
            const float* wq = wb + q * 100;
            #pragma unroll
            for (int t = 0; t < 25; ++t) acc[q] += v[t] * wq[t];
        }
    }
    int o = y * 256 + x;
    #pragma unroll
    for (int q = 0; q < 16; ++q) out[(co0 + q) * HW + o] = fmaxf(acc[q], 0.f);
}

// conv2: 64->64, 3x3 dilation 2, pad 2, relu. grid (256, 4), block 256. 16 co per thread.
__global__ __launch_bounds__(256, 4) void conv2_relu(const float* __restrict__ hin,
        const float* __restrict__ w, const float* __restrict__ b, float* __restrict__ out) {
    int x = threadIdx.x, y = blockIdx.x, co0 = blockIdx.y << 4;
    float acc[16];
    #pragma unroll
    for (int q = 0; q < 16; ++q) acc[q] = b[co0 + q];
    for (int ci = 0; ci < 64; ++ci) {
        float v[9];
        #pragma unroll
        for (int ky = 0; ky < 3; ++ky) {
            int yy = y + (ky - 1) * 2;
            bool yok = (unsigned)yy < 256u;
            const float* row = hin + ci * HW + yy * 256;
            #pragma unroll
            for (int kx = 0; kx < 3; ++kx) {
                int xx = x + (kx - 1) * 2;
                v[ky * 3 + kx] = (yok && (unsigned)xx < 256u) ? row[xx] : 0.f;
            }
        }
        const float* wb = w + co0 * 576 + ci * 9;
        #pragma unroll
        for (int q = 0; q < 16; ++q) {
            const float* wq = wb + q * 576;
            #pragma unroll
            for (int t = 0; t < 9; ++t) acc[q] += v[t] * wq[t];
        }
    }
    int o = y * 256 + x;
    #pragma unroll
    for (int q = 0; q < 16; ++q) out[(co0 + q) * HW + o] = fmaxf(acc[q], 0.f);
}

// fused ConvGRU (1x1 convs + gates). grid (256, 8), block 256. 8 co per thread.
// 48 accumulators: needs the 128-VGPR budget from __launch_bounds__(256,4).
__global__ __launch_bounds__(256, 4) void gru_fused(const float* __restrict__ xin,
        const float* __restrict__ h, const float* __restrict__ ihw, const float* __restrict__ ihb,
        const float* __restrict__ hhw, const float* __restrict__ hhb, float* __restrict__ hout) {
    int x = threadIdx.x, y = blockIdx.x, co0 = blockIdx.y << 3;
    int p = y * 256 + x;
    float ir[8] = {}, iz[8] = {}, in_[8] = {};
    float hr[8] = {}, hz[8] = {}, hn[8] = {};
    #pragma unroll 4
    for (int ci = 0; ci < 64; ++ci) {
        float xv = xin[ci * HW + p];
        float hv = h[ci * HW + p];
        #pragma unroll
        for (int q = 0; q < 8; ++q) {
            int co = co0 + q;
            ir[q] += xv * ihw[co * 64 + ci];
            iz[q] += xv * ihw[(64 + co) * 64 + ci];
            in_[q] += xv * ihw[(128 + co) * 64 + ci];
            hr[q] += hv * hhw[co * 64 + ci];
            hz[q] += hv * hhw[(64 + co) * 64 + ci];
            hn[q] += hv * hhw[(128 + co) * 64 + ci];
        }
    }
    #pragma unroll
    for (int q = 0; q < 8; ++q) {
        int co = co0 + q;
        float r = ir[q] + ihb[co] + hr[q] + hhb[co];
        r = 1.0f / (1.0f + expf(-r));
        float z = iz[q] + ihb[64 + co] + hz[q] + hhb[64 + co];
        z = 1.0f / (1.0f + expf(-z));
        float n = tanhf(in_[q] + ihb[128 + co] + r * (hn[q] + hhb[128 + co]));
        float hcur = h[co * HW + p];
        hout[co * HW + p] = (1.0f - z) * n + z * hcur;
    }
}

// final conv 64->2, 3x3, pad 1, no bias; eta += (d0, d1). grid 256, block 256.
__global__ __launch_bounds__(256, 4) void final_conv_eta(const float* __restrict__ h2,
        const float* __restrict__ w, c32* __restrict__ eta) {
    int x = threadIdx.x, y = blockIdx.x;
    float a0 = 0.f, a1 = 0.f;
    for (int ci = 0; ci < 64; ++ci) {
        float v[9];
        #pragma unroll
        for (int ky = 0; ky < 3; ++ky) {
            int yy = y + ky - 1;
            bool yok = (unsigned)yy < 256u;
            const float* row = h2 + ci * HW + yy * 256;
            #pragma unroll
            for (int kx = 0; kx < 3; ++kx) {
                int xx = x + kx - 1;
                v[ky * 3 + kx] = (yok && (unsigned)xx < 256u) ? row[xx] : 0.f;
            }
        }
        const float* wc = w + ci * 9;
        #pragma unroll
        for (int t = 0; t < 9; ++t) {
            a0 += v[t] * wc[t];
            a1 += v[t] * wc[576 + t];
        }
    }
    int p = y * 256 + x;
    c32 e = eta[p];
    eta[p] = make_float2(e.x + a0, e.y + a1);
}

// ===================== host orchestration =====================
extern "C" void kernel_launch(void* const* d_in, const int* in_sizes, int n_in,
                              void* d_out, int out_size, void* d_ws, size_t ws_size,
                              hipStream_t stream) {
    const c32* pred   = (const c32*)d_in[0];
    const c32* ksp    = (const c32*)d_in[1];
    const c32* sense  = (const c32*)d_in[2];
    const int* mask   = (const int*)d_in[3];
    const float* c1w  = (const float*)d_in[4];
    const float* c1b  = (const float*)d_in[5];
    const float* g1iw = (const float*)d_in[6];
    const float* g1ib = (const float*)d_in[7];
    const float* g1hw = (const float*)d_in[8];
    const float* g1hb = (const float*)d_in[9];
    const float* c2w  = (const float*)d_in[10];
    const float* c2b  = (const float*)d_in[11];
    const float* g2iw = (const float*)d_in[12];
    const float* g2ib = (const float*)d_in[13];
    const float* g2hw = (const float*)d_in[14];
    const float* g2hb = (const float*)d_in[15];
    const float* fw   = (const float*)d_in[16];
    const float* dcw  = (const float*)d_in[17];

    float* w0 = (float*)d_ws;
    c32* base = (c32*)w0;                  // NC*HW complex
    c32* Fk   = base + NC * HW;            // NC*HW complex (cached forward FFT)
    c32* tmp  = Fk + NC * HW;              // NC*HW complex (FFT scratch)
    c32* eta  = tmp + NC * HW;             // HW complex
    float* g  = (float*)(eta + HW);        // 4*HW
    float* x1 = g + 4 * HW;                // NF*HW (also reused as x2)
    float* h1a = x1 + NF * HW;
    float* h1b = h1a + NF * HW;
    float* h2a = h1b + NF * HW;
    float* h2b = h2a + NF * HW;

    (void)hipMemsetAsync(h1a, 0, (size_t)NF * HW * 4, stream);
    (void)hipMemsetAsync(h2a, 0, (size_t)NF * HW * 4, stream);

    dim3 B(256);
    const int gCHW = NC * HW / 256;   // 3072
    const int gHW  = HW / 256;        // 256
    const int gROW = NC * 256 / 4;    // 768
    dim3 gCOL(64, NC);
    dim3 gC16(256, 4);
    dim3 gGRU(256, 8);

    // eta0 = sum_c ifft2c(pred_c) * conj(sense_c)
    k_pre<<<gCHW, B, 0, stream>>>(pred, tmp);
    fft_rows<<<gROW, B, 0, stream>>>(tmp, -1.0f);   // inverse: conj twiddles
    fft_cols<<<gCOL, B, 0, stream>>>(tmp, -1.0f);
    k_combine_eta0<<<gHW, B, 0, stream>>>(tmp, sense, eta);

    k_base<<<gCHW, B, 0, stream>>>(ksp, pred, mask, dcw, base);

    // F_0 (unnormalized, S-folded): G = FFT2u(S*(eta*sense))
    k_expand<<<gCHW, B, 0, stream>>>(eta, sense, Fk);
    fft_rows<<<gROW, B, 0, stream>>>(Fk, 1.0f);     // forward
    fft_cols<<<gCOL, B, 0, stream>>>(Fk, 1.0f);

    float* h1c = h1a; float* h1n = h1b;
    float* h2c = h2a; float* h2n = h2b;
    c32* outp = (c32*)d_out;

    for (int t = 0; t < NT; ++t) {
        // gradient from cached F_{t-1}
        k_resid<<<gCHW, B, 0, stream>>>(Fk, ksp, mask, tmp);
        fft_rows<<<gROW, B, 0, stream>>>(tmp, -1.0f);
        fft_cols<<<gCOL, B, 0, stream>>>(tmp, -1.0f);
        k_grad_g<<<gHW, B, 0, stream>>>(tmp, sense, eta, g);

        // network
        conv1_relu<<<gC16, B, 0, stream>>>(g, c1w, c1b, x1);
        gru_fused<<<gGRU, B, 0, stream>>>(x1, h1c, g1iw, g1ib, g1hw, g1hb, h1n);
        { float* s = h1c; h1c = h1n; h1n = s; }
        conv2_relu<<<gC16, B, 0, stream>>>(h1c, c2w, c2b, x1);  // x1 reused as x2
        gru_fused<<<gGRU, B, 0, stream>>>(x1, h2c, g2iw, g2ib, g2hw, g2hb, h2n);
        { float* s = h2c; h2c = h2n; h2n = s; }
        final_conv_eta<<<256, B, 0, stream>>>(h2c, fw, eta);

        // F_t for this step's output (and next step's gradient)
        k_expand<<<gCHW, B, 0, stream>>>(eta, sense, Fk);
        fft_rows<<<gROW, B, 0, stream>>>(Fk, 1.0f);
        fft_cols<<<gCOL, B, 0, stream>>>(Fk, 1.0f);
        k_out<<<gCHW, B, 0, stream>>>(base, Fk, outp + (size_t)t * NC * HW);
    }
}

// Round 5
// 2367.922 us; speedup vs baseline: 1.9860x; 1.5922x over previous
//
#include <hip/hip_runtime.h>

#define HW 65536
#define NC 12
#define NF 64
#define NT 8

typedef float2 c32;
typedef __attribute__((ext_vector_type(8))) short bf16x8;   // 8 bf16 = 4 VGPR
typedef __attribute__((ext_vector_type(4))) float f32x4;    // MFMA C/D

__device__ __forceinline__ float ssign(int p) {
    return ((p ^ (p >> 8)) & 1) ? -1.0f : 1.0f;
}

__device__ __forceinline__ short f2bf(float f) {   // RNE float->bf16
    union { float f; unsigned u; } v; v.f = f;
    unsigned r = (v.u + 0x7FFFu + ((v.u >> 16) & 1u)) >> 16;
    return (short)r;
}

// ===================== 256-point radix-2 DIT FFT in LDS =====================
__device__ __forceinline__ void fft256_stages(c32* X, const c32* tw, int j, float conjf) {
    #pragma unroll
    for (int s = 1; s <= 8; ++s) {
        const int half = 1 << (s - 1);
        #pragma unroll
        for (int b = 0; b < 2; ++b) {
            int idx = j + (b << 6);
            int grp = idx >> (s - 1);
            int pos = idx & (half - 1);
            int i0 = (grp << s) + pos;
            int i1 = i0 + half;
            c32 w = tw[pos << (8 - s)];
            float wy = conjf * w.y;
            c32 a = X[i0], cc = X[i1];
            c32 t = make_float2(w.x * cc.x - wy * cc.y, w.x * cc.y + wy * cc.x);
            X[i0] = make_float2(a.x + t.x, a.y + t.y);
            X[i1] = make_float2(a.x - t.x, a.y - t.y);
        }
        __syncthreads();
    }
}

__device__ __forceinline__ void build_tw(c32* tw, int tid) {
    if (tid < 128) {
        float a = -3.14159265358979323846f * (float)tid * (1.0f / 128.0f);
        float sv, cv;
        sincosf(a, &sv, &cv);
        tw[tid] = make_float2(cv, sv);
    }
}

__global__ __launch_bounds__(256) void fft_rows(c32* __restrict__ buf, float conjf) {
    __shared__ c32 lds[4][256];
    __shared__ c32 tw[128];
    int tid = threadIdx.x;
    build_tw(tw, tid);
    int wid = tid >> 6, j = tid & 63;
    c32* rp = buf + (size_t)(blockIdx.x * 4 + wid) * 256;
    c32* X = lds[wid];
    #pragma unroll
    for (int e = 0; e < 4; ++e) {
        int n = (e << 6) + j;
        X[__brev((unsigned)n) >> 24] = rp[n];
    }
    __syncthreads();
    fft256_stages(X, tw, j, conjf);
    #pragma unroll
    for (int e = 0; e < 4; ++e) {
        int n = (e << 6) + j;
        rp[n] = X[n];
    }
}

__global__ __launch_bounds__(256) void fft_cols(c32* __restrict__ buf, float conjf) {
    __shared__ c32 lds[4][257];
    __shared__ c32 tw[128];
    int tid = threadIdx.x;
    build_tw(tw, tid);
    c32* ip = buf + (size_t)blockIdx.y * HW;
    int x0 = blockIdx.x * 4;
    int cl = tid & 3, yb = tid >> 2;
    #pragma unroll
    for (int e = 0; e < 4; ++e) {
        int y = yb + (e << 6);
        lds[cl][__brev((unsigned)y) >> 24] = ip[y * 256 + x0 + cl];
    }
    __syncthreads();
    int col = tid >> 6, j = tid & 63;
    fft256_stages(&lds[col][0], tw, j, conjf);
    #pragma unroll
    for (int e = 0; e < 4; ++e) {
        int y = yb + (e << 6);
        ip[y * 256 + x0 + cl] = lds[cl][y];
    }
}

// ===================== pointwise kernels =====================
__global__ __launch_bounds__(256) void k_pre(const c32* __restrict__ pred, c32* __restrict__ tmp) {
    int i = blockIdx.x * 256 + threadIdx.x;
    int p = i & (HW - 1);
    float s = ssign(p);
    c32 v = pred[i];
    tmp[i] = make_float2(s * v.x, s * v.y);
}

__global__ __launch_bounds__(256) void k_combine_eta0(const c32* __restrict__ tmp,
        const c32* __restrict__ sense, c32* __restrict__ eta) {
    int p = blockIdx.x * 256 + threadIdx.x;
    float ax = 0.f, ay = 0.f;
    for (int c = 0; c < NC; ++c) {
        c32 t = tmp[c * HW + p], s = sense[c * HW + p];
        ax += t.x * s.x + t.y * s.y;
        ay += t.y * s.x - t.x * s.y;
    }
    float sc = ssign(p) * (1.0f / 256.0f);
    eta[p] = make_float2(ax * sc, ay * sc);
}

__global__ __launch_bounds__(256) void k_base(const c32* __restrict__ ksp,
        const c32* __restrict__ pred, const int* __restrict__ mask,
        const float* __restrict__ dcw, c32* __restrict__ base) {
    int i = blockIdx.x * 256 + threadIdx.x;
    int p = i & (HW - 1);
    c32 k = ksp[i];
    c32 o = k;
    if (mask[p]) {
        float w = dcw[0];
        c32 pr = pred[i];
        o.x -= (pr.x - k.x) * w;
        o.y -= (pr.y - k.y) * w;
    }
    base[i] = o;
}

__global__ __launch_bounds__(256) void k_expand(const c32* __restrict__ eta,
        const c32* __restrict__ sense, c32* __restrict__ Fk) {
    int i = blockIdx.x * 256 + threadIdx.x;
    int p = i & (HW - 1);
    float s = ssign(p);
    c32 e = eta[p], sn = sense[i];
    Fk[i] = make_float2(s * (e.x * sn.x - e.y * sn.y), s * (e.x * sn.y + e.y * sn.x));
}

__global__ __launch_bounds__(256) void k_resid(const c32* __restrict__ Fk,
        const c32* __restrict__ ksp, const int* __restrict__ mask, c32* __restrict__ tmp) {
    int i = blockIdx.x * 256 + threadIdx.x;
    int p = i & (HW - 1);
    if (!mask[p]) { tmp[i] = make_float2(0.f, 0.f); return; }
    float s = ssign(p);
    c32 g = Fk[i], k = ksp[i];
    tmp[i] = make_float2(g.x * (1.0f / 256.0f) - s * k.x,
                         g.y * (1.0f / 256.0f) - s * k.y);
}

__global__ __launch_bounds__(256) void k_grad_g(const c32* __restrict__ tmp,
        const c32* __restrict__ sense, const c32* __restrict__ eta, float* __restrict__ g) {
    int p = blockIdx.x * 256 + threadIdx.x;
    float ax = 0.f, ay = 0.f;
    for (int c = 0; c < NC; ++c) {
        c32 t = tmp[c * HW + p], s = sense[c * HW + p];
        ax += t.x * s.x + t.y * s.y;
        ay += t.y * s.x - t.x * s.y;
    }
    float sc = ssign(p) * (1.0f / 256.0f);
    c32 e = eta[p];
    g[0 * HW + p] = e.x;
    g[1 * HW + p] = e.y;
    g[2 * HW + p] = ax * sc;
    g[3 * HW + p] = ay * sc;
}

__global__ __launch_bounds__(256) void k_out(const c32* __restrict__ base,
        const c32* __restrict__ Fk, c32* __restrict__ outp) {
    int i = blockIdx.x * 256 + threadIdx.x;
    int p = i & (HW - 1);
    float sc = ssign(p) * (1.0f / 256.0f);
    c32 g = Fk[i], b = base[i];
    outp[i] = make_float2(b.x - sc * g.x, b.y - sc * g.y);
}

// ===================== convolutions (unchanged from passing round) ==========
__global__ __launch_bounds__(256, 4) void conv1_relu(const float* __restrict__ g,
        const float* __restrict__ w, const float* __restrict__ b, float* __restrict__ out) {
    int x = threadIdx.x, y = blockIdx.x, co0 = blockIdx.y << 4;
    float acc[16];
    #pragma unroll
    for (int q = 0; q < 16; ++q) acc[q] = b[co0 + q];
    #pragma unroll
    for (int ci = 0; ci < 4; ++ci) {
        float v[25];
        #pragma unroll
        for (int ky = 0; ky < 5; ++ky) {
            int yy = y + ky - 2;
            bool yok = (unsigned)yy < 256u;
            const float* row = g + ci * HW + yy * 256;
            #pragma unroll
            for (int kx = 0; kx < 5; ++kx) {
                int xx = x + kx - 2;
                v[ky * 5 + kx] = (yok && (unsigned)xx < 256u) ? row[xx] : 0.f;
            }
        }
        const float* wb = w + co0 * 100 + ci * 25;
        #pragma unroll
        for (int q = 0; q < 16; ++q) {
            const float* wq = wb + q * 100;
            #pragma unroll
            for (int t = 0; t < 25; ++t) acc[q] += v[t] * wq[t];
        }
    }
    int o = y * 256 + x;
    #pragma unroll
    for (int q = 0; q < 16; ++q) out[(co0 + q) * HW + o] = fmaxf(acc[q], 0.f);
}

__global__ __launch_bounds__(256, 4) void conv2_relu(const float* __restrict__ hin,
        const float* __restrict__ w, const float* __restrict__ b, float* __restrict__ out) {
    int x = threadIdx.x, y = blockIdx.x, co0 = blockIdx.y << 4;
    float acc[16];
    #pragma unroll
    for (int q = 0; q < 16; ++q) acc[q] = b[co0 + q];
    for (int ci = 0; ci < 64; ++ci) {
        float v[9];
        #pragma unroll
        for (int ky = 0; ky < 3; ++ky) {
            int yy = y + (ky - 1) * 2;
            bool yok = (unsigned)yy < 256u;
            const float* row = hin + ci * HW + yy * 256;
            #pragma unroll
            for (int kx = 0; kx < 3; ++kx) {
                int xx = x + (kx - 1) * 2;
                v[ky * 3 + kx] = (yok && (unsigned)xx < 256u) ? row[xx] : 0.f;
            }
        }
        const float* wb = w + co0 * 576 + ci * 9;
        #pragma unroll
        for (int q = 0; q < 16; ++q) {
            const float* wq = wb + q * 576;
            #pragma unroll
            for (int t = 0; t < 9; ++t) acc[q] += v[t] * wq[t];
        }
    }
    int o = y * 256 + x;
    #pragma unroll
    for (int q = 0; q < 16; ++q) out[(co0 + q) * HW + o] = fmaxf(acc[q], 0.f);
}

// ===================== GRU via MFMA =====================
// Prep: padded weight matrix W2[256][128] bf16 + folded biases[256].
// rows 0-63:   r-gate  [Wih_r | Whh_r]   bias = ihb_r + hhb_r
// rows 64-127: z-gate  [Wih_z | Whh_z]   bias = ihb_z + hhb_z
// rows 128-191: i_n    [Wih_n |   0  ]   bias = ihb_n
// rows 192-255: h_n    [  0   | Whh_n]   bias = hhb_n
__global__ __launch_bounds__(128) void k_prep_gru(const float* __restrict__ ihw,
        const float* __restrict__ ihb, const float* __restrict__ hhw,
        const float* __restrict__ hhb, short* __restrict__ w2, float* __restrict__ bias) {
    int k = threadIdx.x;      // 0..127
    int r = blockIdx.x;       // 0..255
    int g = r >> 6, co = r & 63;
    float v = 0.f;
    if (g == 0)      v = (k < 64) ? ihw[co * 64 + k]         : hhw[co * 64 + k - 64];
    else if (g == 1) v = (k < 64) ? ihw[(64 + co) * 64 + k]  : hhw[(64 + co) * 64 + k - 64];
    else if (g == 2) v = (k < 64) ? ihw[(128 + co) * 64 + k] : 0.f;
    else             v = (k < 64) ? 0.f : hhw[(128 + co) * 64 + k - 64];
    w2[r * 128 + k] = f2bf(v);
    if (k == 0) {
        float b = (g == 0) ? ihb[co] + hhb[co]
                : (g == 1) ? ihb[64 + co] + hhb[64 + co]
                : (g == 2) ? ihb[128 + co] : hhb[128 + co];
        bias[r] = b;
    }
}

// grid: 1024 blocks x 256 threads. Block = 64 px; wave w = co [16w,16w+16)
// across all 4 gate types (m-tiles at rows {16w, 64+16w, 128+16w, 192+16w}).
// i_n uses only K-tiles 0,1 (X); h_n only 2,3 (H) -> 12 MFMA per n-tile.
__global__ __launch_bounds__(256, 2) void gru_mfma(const float* __restrict__ xin,
        const float* __restrict__ h, const short* __restrict__ w2,
        const float* __restrict__ bias, float* __restrict__ hout) {
    int wv = threadIdx.x >> 6, l = threadIdx.x & 63;
    int lr = l & 15, lg = l >> 4;
    int px0 = blockIdx.x * 64;

    // A fragments: lane holds row m = lr, k = kt*32 + lg*8 + j (j=0..7)
    bf16x8 A0[4], A1[4], A2[2], A3[2];
    {
        const short* w0 = w2 + (0   + wv * 16 + lr) * 128 + lg * 8;
        const short* w1 = w2 + (64  + wv * 16 + lr) * 128 + lg * 8;
        const short* w2p = w2 + (128 + wv * 16 + lr) * 128 + lg * 8;
        const short* w3 = w2 + (192 + wv * 16 + lr) * 128 + lg * 8;
        #pragma unroll
        for (int kt = 0; kt < 4; ++kt) {
            A0[kt] = *(const bf16x8*)(w0 + kt * 32);
            A1[kt] = *(const bf16x8*)(w1 + kt * 32);
        }
        A2[0] = *(const bf16x8*)(w2p);          A2[1] = *(const bf16x8*)(w2p + 32);
        A3[0] = *(const bf16x8*)(w3 + 64);      A3[1] = *(const bf16x8*)(w3 + 96);
    }

    f32x4 C0[4], C1[4], C2[4], C3[4];
    #pragma unroll
    for (int nt = 0; nt < 4; ++nt) {
        C0[nt] = (f32x4){0.f, 0.f, 0.f, 0.f};
        C1[nt] = (f32x4){0.f, 0.f, 0.f, 0.f};
        C2[nt] = (f32x4){0.f, 0.f, 0.f, 0.f};
        C3[nt] = (f32x4){0.f, 0.f, 0.f, 0.f};
    }

    #pragma unroll
    for (int nt = 0; nt < 4; ++nt) {
        int px = px0 + nt * 16 + lr;
        // B fragments: lane holds col n = lr, k = kt*32 + lg*8 + j
        bf16x8 B[4];
        #pragma unroll
        for (int kt = 0; kt < 4; ++kt) {
            const float* src = (kt < 2) ? xin + (size_t)(kt * 32 + lg * 8) * HW + px
                                        : h   + (size_t)((kt - 2) * 32 + lg * 8) * HW + px;
            #pragma unroll
            for (int j = 0; j < 8; ++j) B[kt][j] = f2bf(src[(size_t)j * HW]);
        }
        #pragma unroll
        for (int kt = 0; kt < 4; ++kt) {
            C0[nt] = __builtin_amdgcn_mfma_f32_16x16x32_bf16(A0[kt], B[kt], C0[nt], 0, 0, 0);
            C1[nt] = __builtin_amdgcn_mfma_f32_16x16x32_bf16(A1[kt], B[kt], C1[nt], 0, 0, 0);
        }
        C2[nt] = __builtin_amdgcn_mfma_f32_16x16x32_bf16(A2[0], B[0], C2[nt], 0, 0, 0);
        C2[nt] = __builtin_amdgcn_mfma_f32_16x16x32_bf16(A2[1], B[1], C2[nt], 0, 0, 0);
        C3[nt] = __builtin_amdgcn_mfma_f32_16x16x32_bf16(A3[0], B[2], C3[nt], 0, 0, 0);
        C3[nt] = __builtin_amdgcn_mfma_f32_16x16x32_bf16(A3[1], B[3], C3[nt], 0, 0, 0);
    }

    // Epilogue. C/D layout: col = lr (px), row = lg*4 + i (co within 16).
    int co = wv * 16 + lg * 4;
    float br[4], bz[4], bin_[4], bhn[4];
    #pragma unroll
    for (int i = 0; i < 4; ++i) {
        br[i]   = bias[co + i];
        bz[i]   = bias[64 + co + i];
        bin_[i] = bias[128 + co + i];
        bhn[i]  = bias[192 + co + i];
    }
    #pragma unroll
    for (int nt = 0; nt < 4; ++nt) {
        int px = px0 + nt * 16 + lr;
        #pragma unroll
        for (int i = 0; i < 4; ++i) {
            float r = 1.0f / (1.0f + expf(-(C0[nt][i] + br[i])));
            float z = 1.0f / (1.0f + expf(-(C1[nt][i] + bz[i])));
            float nn = tanhf(C2[nt][i] + bin_[i] + r * (C3[nt][i] + bhn[i]));
            float ho = h[(size_t)(co + i) * HW + px];
            hout[(size_t)(co + i) * HW + px] = (1.0f - z) * nn + z * ho;
        }
    }
}

// final conv 64->2, 3x3, pad 1, no bias; eta += (d0, d1).
__global__ __launch_bounds__(256, 4) void final_conv_eta(const float* __restrict__ h2,
        const float* __restrict__ w, c32* __restrict__ eta) {
    int x = threadIdx.x, y = blockIdx.x;
    float a0 = 0.f, a1 = 0.f;
    for (int ci = 0; ci < 64; ++ci) {
        float v[9];
        #pragma unroll
        for (int ky = 0; ky < 3; ++ky) {
            int yy = y + ky - 1;
            bool yok = (unsigned)yy < 256u;
            const float* row = h2 + ci * HW + yy * 256;
            #pragma unroll
            for (int kx = 0; kx < 3; ++kx) {
                int xx = x + kx - 1;
                v[ky * 3 + kx] = (yok && (unsigned)xx < 256u) ? row[xx] : 0.f;
            }
        }
        const float* wc = w + ci * 9;
        #pragma unroll
        for (int t = 0; t < 9; ++t) {
            a0 += v[t] * wc[t];
            a1 += v[t] * wc[576 + t];
        }
    }
    int p = y * 256 + x;
    c32 e = eta[p];
    eta[p] = make_float2(e.x + a0, e.y + a1);
}

// ===================== host orchestration =====================
extern "C" void kernel_launch(void* const* d_in, const int* in_sizes, int n_in,
                              void* d_out, int out_size, void* d_ws, size_t ws_size,
                              hipStream_t stream) {
    const c32* pred   = (const c32*)d_in[0];
    const c32* ksp    = (const c32*)d_in[1];
    const c32* sense  = (const c32*)d_in[2];
    const int* mask   = (const int*)d_in[3];
    const float* c1w  = (const float*)d_in[4];
    const float* c1b  = (const float*)d_in[5];
    const float* g1iw = (const float*)d_in[6];
    const float* g1ib = (const float*)d_in[7];
    const float* g1hw = (const float*)d_in[8];
    const float* g1hb = (const float*)d_in[9];
    const float* c2w  = (const float*)d_in[10];
    const float* c2b  = (const float*)d_in[11];
    const float* g2iw = (const float*)d_in[12];
    const float* g2ib = (const float*)d_in[13];
    const float* g2hw = (const float*)d_in[14];
    const float* g2hb = (const float*)d_in[15];
    const float* fw   = (const float*)d_in[16];
    const float* dcw  = (const float*)d_in[17];

    float* w0 = (float*)d_ws;
    c32* base = (c32*)w0;                  // NC*HW complex
    c32* Fk   = base + NC * HW;            // NC*HW complex
    c32* tmp  = Fk + NC * HW;              // NC*HW complex
    c32* eta  = tmp + NC * HW;             // HW complex
    float* g  = (float*)(eta + HW);        // 4*HW
    float* x1 = g + 4 * HW;                // NF*HW
    float* h1a = x1 + NF * HW;
    float* h1b = h1a + NF * HW;
    float* h2a = h1b + NF * HW;
    float* h2b = h2a + NF * HW;
    short* w2a  = (short*)(h2b + NF * HW); // 256*128 bf16
    short* w2b  = w2a + 256 * 128;
    float* biasA = (float*)(w2b + 256 * 128);
    float* biasB = biasA + 256;

    (void)hipMemsetAsync(h1a, 0, (size_t)NF * HW * 4, stream);
    (void)hipMemsetAsync(h2a, 0, (size_t)NF * HW * 4, stream);

    dim3 B(256);
    const int gCHW = NC * HW / 256;   // 3072
    const int gHW  = HW / 256;        // 256
    const int gROW = NC * 256 / 4;    // 768
    dim3 gCOL(64, NC);
    dim3 gC16(256, 4);
    const int gGRU = HW / 64;         // 1024 blocks

    // GRU weight prep (cheap, once per call)
    k_prep_gru<<<256, 128, 0, stream>>>(g1iw, g1ib, g1hw, g1hb, w2a, biasA);
    k_prep_gru<<<256, 128, 0, stream>>>(g2iw, g2ib, g2hw, g2hb, w2b, biasB);

    // eta0 = sum_c ifft2c(pred_c) * conj(sense_c)
    k_pre<<<gCHW, B, 0, stream>>>(pred, tmp);
    fft_rows<<<gROW, B, 0, stream>>>(tmp, -1.0f);
    fft_cols<<<gCOL, B, 0, stream>>>(tmp, -1.0f);
    k_combine_eta0<<<gHW, B, 0, stream>>>(tmp, sense, eta);

    k_base<<<gCHW, B, 0, stream>>>(ksp, pred, mask, dcw, base);

    // F_0: G = FFT2u(S*(eta*sense))
    k_expand<<<gCHW, B, 0, stream>>>(eta, sense, Fk);
    fft_rows<<<gROW, B, 0, stream>>>(Fk, 1.0f);
    fft_cols<<<gCOL, B, 0, stream>>>(Fk, 1.0f);

    float* h1c = h1a; float* h1n = h1b;
    float* h2c = h2a; float* h2n = h2b;
    c32* outp = (c32*)d_out;

    for (int t = 0; t < NT; ++t) {
        // gradient from cached F_{t-1}
        k_resid<<<gCHW, B, 0, stream>>>(Fk, ksp, mask, tmp);
        fft_rows<<<gROW, B, 0, stream>>>(tmp, -1.0f);
        fft_cols<<<gCOL, B, 0, stream>>>(tmp, -1.0f);
        k_grad_g<<<gHW, B, 0, stream>>>(tmp, sense, eta, g);

        // network
        conv1_relu<<<gC16, B, 0, stream>>>(g, c1w, c1b, x1);
        gru_mfma<<<gGRU, B, 0, stream>>>(x1, h1c, w2a, biasA, h1n);
        { float* s = h1c; h1c = h1n; h1n = s; }
        conv2_relu<<<gC16, B, 0, stream>>>(h1c, c2w, c2b, x1);
        gru_mfma<<<gGRU, B, 0, stream>>>(x1, h2c, w2b, biasB, h2n);
        { float* s = h2c; h2c = h2n; h2n = s; }
        final_conv_eta<<<256, B, 0, stream>>>(h2c, fw, eta);

        // F_t for this step's output (and next step's gradient)
        k_expand<<<gCHW, B, 0, stream>>>(eta, sense, Fk);
        fft_rows<<<gROW, B, 0, stream>>>(Fk, 1.0f);
        fft_cols<<<gCOL, B, 0, stream>>>(Fk, 1.0f);
        k_out<<<gCHW, B, 0, stream>>>(base, Fk, outp + (size_t)t * NC * HW);
    }
}

// Round 6
// 1926.989 us; speedup vs baseline: 2.4404x; 1.2288x over previous
//
#include <hip/hip_runtime.h>

#define HW 65536
#define NC 12
#define NF 64
#define NT 8

typedef float2 c32;
typedef __attribute__((ext_vector_type(8))) short bf16x8;   // 8 bf16 = 4 VGPR
typedef __attribute__((ext_vector_type(4))) float f32x4;    // MFMA C/D

__device__ __forceinline__ float ssign(int p) {
    return ((p ^ (p >> 8)) & 1) ? -1.0f : 1.0f;
}

__device__ __forceinline__ short f2bf(float f) {   // RNE float->bf16
    union { float f; unsigned u; } v; v.f = f;
    unsigned r = (v.u + 0x7FFFu + ((v.u >> 16) & 1u)) >> 16;
    return (short)r;
}

// ===================== 256-point radix-2 DIT FFT in LDS =====================
__device__ __forceinline__ void fft256_stages(c32* X, const c32* tw, int j, float conjf) {
    #pragma unroll
    for (int s = 1; s <= 8; ++s) {
        const int half = 1 << (s - 1);
        #pragma unroll
        for (int b = 0; b < 2; ++b) {
            int idx = j + (b << 6);
            int grp = idx >> (s - 1);
            int pos = idx & (half - 1);
            int i0 = (grp << s) + pos;
            int i1 = i0 + half;
            c32 w = tw[pos << (8 - s)];
            float wy = conjf * w.y;
            c32 a = X[i0], cc = X[i1];
            c32 t = make_float2(w.x * cc.x - wy * cc.y, w.x * cc.y + wy * cc.x);
            X[i0] = make_float2(a.x + t.x, a.y + t.y);
            X[i1] = make_float2(a.x - t.x, a.y - t.y);
        }
        __syncthreads();
    }
}

__device__ __forceinline__ void build_tw(c32* tw, int tid) {
    if (tid < 128) {
        float a = -3.14159265358979323846f * (float)tid * (1.0f / 128.0f);
        float sv, cv;
        sincosf(a, &sv, &cv);
        tw[tid] = make_float2(cv, sv);
    }
}

__global__ __launch_bounds__(256) void fft_rows(c32* __restrict__ buf, float conjf) {
    __shared__ c32 lds[4][256];
    __shared__ c32 tw[128];
    int tid = threadIdx.x;
    build_tw(tw, tid);
    int wid = tid >> 6, j = tid & 63;
    c32* rp = buf + (size_t)(blockIdx.x * 4 + wid) * 256;
    c32* X = lds[wid];
    #pragma unroll
    for (int e = 0; e < 4; ++e) {
        int n = (e << 6) + j;
        X[__brev((unsigned)n) >> 24] = rp[n];
    }
    __syncthreads();
    fft256_stages(X, tw, j, conjf);
    #pragma unroll
    for (int e = 0; e < 4; ++e) {
        int n = (e << 6) + j;
        rp[n] = X[n];
    }
}

__global__ __launch_bounds__(256) void fft_cols(c32* __restrict__ buf, float conjf) {
    __shared__ c32 lds[4][257];
    __shared__ c32 tw[128];
    int tid = threadIdx.x;
    build_tw(tw, tid);
    c32* ip = buf + (size_t)blockIdx.y * HW;
    int x0 = blockIdx.x * 4;
    int cl = tid & 3, yb = tid >> 2;
    #pragma unroll
    for (int e = 0; e < 4; ++e) {
        int y = yb + (e << 6);
        lds[cl][__brev((unsigned)y) >> 24] = ip[y * 256 + x0 + cl];
    }
    __syncthreads();
    int col = tid >> 6, j = tid & 63;
    fft256_stages(&lds[col][0], tw, j, conjf);
    #pragma unroll
    for (int e = 0; e < 4; ++e) {
        int y = yb + (e << 6);
        ip[y * 256 + x0 + cl] = lds[cl][y];
    }
}

// ===================== pointwise kernels =====================
__global__ __launch_bounds__(256) void k_pre(const c32* __restrict__ pred, c32* __restrict__ tmp) {
    int i = blockIdx.x * 256 + threadIdx.x;
    int p = i & (HW - 1);
    float s = ssign(p);
    c32 v = pred[i];
    tmp[i] = make_float2(s * v.x, s * v.y);
}

__global__ __launch_bounds__(256) void k_combine_eta0(const c32* __restrict__ tmp,
        const c32* __restrict__ sense, c32* __restrict__ eta) {
    int p = blockIdx.x * 256 + threadIdx.x;
    float ax = 0.f, ay = 0.f;
    for (int c = 0; c < NC; ++c) {
        c32 t = tmp[c * HW + p], s = sense[c * HW + p];
        ax += t.x * s.x + t.y * s.y;
        ay += t.y * s.x - t.x * s.y;
    }
    float sc = ssign(p) * (1.0f / 256.0f);
    eta[p] = make_float2(ax * sc, ay * sc);
}

__global__ __launch_bounds__(256) void k_base(const c32* __restrict__ ksp,
        const c32* __restrict__ pred, const int* __restrict__ mask,
        const float* __restrict__ dcw, c32* __restrict__ base) {
    int i = blockIdx.x * 256 + threadIdx.x;
    int p = i & (HW - 1);
    c32 k = ksp[i];
    c32 o = k;
    if (mask[p]) {
        float w = dcw[0];
        c32 pr = pred[i];
        o.x -= (pr.x - k.x) * w;
        o.y -= (pr.y - k.y) * w;
    }
    base[i] = o;
}

__global__ __launch_bounds__(256) void k_expand(const c32* __restrict__ eta,
        const c32* __restrict__ sense, c32* __restrict__ Fk) {
    int i = blockIdx.x * 256 + threadIdx.x;
    int p = i & (HW - 1);
    float s = ssign(p);
    c32 e = eta[p], sn = sense[i];
    Fk[i] = make_float2(s * (e.x * sn.x - e.y * sn.y), s * (e.x * sn.y + e.y * sn.x));
}

__global__ __launch_bounds__(256) void k_resid(const c32* __restrict__ Fk,
        const c32* __restrict__ ksp, const int* __restrict__ mask, c32* __restrict__ tmp) {
    int i = blockIdx.x * 256 + threadIdx.x;
    int p = i & (HW - 1);
    if (!mask[p]) { tmp[i] = make_float2(0.f, 0.f); return; }
    float s = ssign(p);
    c32 g = Fk[i], k = ksp[i];
    tmp[i] = make_float2(g.x * (1.0f / 256.0f) - s * k.x,
                         g.y * (1.0f / 256.0f) - s * k.y);
}

__global__ __launch_bounds__(256) void k_grad_g(const c32* __restrict__ tmp,
        const c32* __restrict__ sense, const c32* __restrict__ eta, float* __restrict__ g) {
    int p = blockIdx.x * 256 + threadIdx.x;
    float ax = 0.f, ay = 0.f;
    for (int c = 0; c < NC; ++c) {
        c32 t = tmp[c * HW + p], s = sense[c * HW + p];
        ax += t.x * s.x + t.y * s.y;
        ay += t.y * s.x - t.x * s.y;
    }
    float sc = ssign(p) * (1.0f / 256.0f);
    c32 e = eta[p];
    g[0 * HW + p] = e.x;
    g[1 * HW + p] = e.y;
    g[2 * HW + p] = ax * sc;
    g[3 * HW + p] = ay * sc;
}

__global__ __launch_bounds__(256) void k_out(const c32* __restrict__ base,
        const c32* __restrict__ Fk, c32* __restrict__ outp) {
    int i = blockIdx.x * 256 + threadIdx.x;
    int p = i & (HW - 1);
    float sc = ssign(p) * (1.0f / 256.0f);
    c32 g = Fk[i], b = base[i];
    outp[i] = make_float2(b.x - sc * g.x, b.y - sc * g.y);
}

// ===================== conv1 (scalar, unchanged) =====================
__global__ __launch_bounds__(256, 4) void conv1_relu(const float* __restrict__ g,
        const float* __restrict__ w, const float* __restrict__ b, float* __restrict__ out) {
    int x = threadIdx.x, y = blockIdx.x, co0 = blockIdx.y << 4;
    float acc[16];
    #pragma unroll
    for (int q = 0; q < 16; ++q) acc[q] = b[co0 + q];
    #pragma unroll
    for (int ci = 0; ci < 4; ++ci) {
        float v[25];
        #pragma unroll
        for (int ky = 0; ky < 5; ++ky) {
            int yy = y + ky - 2;
            bool yok = (unsigned)yy < 256u;
            const float* row = g + ci * HW + yy * 256;
            #pragma unroll
            for (int kx = 0; kx < 5; ++kx) {
                int xx = x + kx - 2;
                v[ky * 5 + kx] = (yok && (unsigned)xx < 256u) ? row[xx] : 0.f;
            }
        }
        const float* wb = w + co0 * 100 + ci * 25;
        #pragma unroll
        for (int q = 0; q < 16; ++q) {
            const float* wq = wb + q * 100;
            #pragma unroll
            for (int t = 0; t < 25; ++t) acc[q] += v[t] * wq[t];
        }
    }
    int o = y * 256 + x;
    #pragma unroll
    for (int q = 0; q < 16; ++q) out[(co0 + q) * HW + o] = fmaxf(acc[q], 0.f);
}

// ===================== conv2 via MFMA =====================
// Prep: wA[tap][co][ci] bf16 from OIHW c2w[co][ci][ky][kx]; tap = ky*3+kx.
__global__ __launch_bounds__(256) void k_prep_c2(const float* __restrict__ w,
        short* __restrict__ wA) {
    int i = blockIdx.x * 256 + threadIdx.x;     // 36864 total
    int tap = i >> 12, co = (i >> 6) & 63, ci = i & 63;
    wA[i] = f2bf(w[co * 576 + ci * 9 + tap]);
}

// grid: 1024 blocks (4 x-seg x 256 y), 256 thr (4 waves). Wave w: co [16w,16w+16).
// out[co][px] = relu( sum_tap W_tap @ hT_shift(tap) + bias )
// hT: [px][64ci] bf16 (transposed copy written by gru_mfma).
__global__ __launch_bounds__(256, 2) void conv2_mfma(const short* __restrict__ hT,
        const short* __restrict__ wA, const float* __restrict__ bias,
        float* __restrict__ out) {
    int wv = threadIdx.x >> 6, l = threadIdx.x & 63;
    int lr = l & 15, lg = l >> 4;
    int y = blockIdx.x >> 2;
    int x0 = (blockIdx.x & 3) << 6;

    f32x4 C[4];
    #pragma unroll
    for (int nt = 0; nt < 4; ++nt) C[nt] = (f32x4){0.f, 0.f, 0.f, 0.f};

    #pragma unroll
    for (int tap = 0; tap < 9; ++tap) {
        const int dy = (tap / 3 - 1) * 2, dx = (tap % 3 - 1) * 2;
        int yy = y + dy;
        bool yok = (unsigned)yy < 256u;
        const short* pA = wA + (size_t)(tap * 64 + wv * 16 + lr) * 64 + lg * 8;
        bf16x8 A0 = *(const bf16x8*)(pA);
        bf16x8 A1 = *(const bf16x8*)(pA + 32);
        #pragma unroll
        for (int nt = 0; nt < 4; ++nt) {
            int xx = x0 + nt * 16 + lr + dx;
            bool ok = yok && ((unsigned)xx < 256u);
            int pcl = ok ? (yy * 256 + xx) : 0;           // clamped addr, masked use
            const short* pB = hT + (size_t)pcl * 64 + lg * 8;
            bf16x8 B0 = {}, B1 = {};
            if (ok) {
                B0 = *(const bf16x8*)(pB);
                B1 = *(const bf16x8*)(pB + 32);
            }
            C[nt] = __builtin_amdgcn_mfma_f32_16x16x32_bf16(A0, B0, C[nt], 0, 0, 0);
            C[nt] = __builtin_amdgcn_mfma_f32_16x16x32_bf16(A1, B1, C[nt], 0, 0, 0);
        }
    }
    int co = wv * 16 + lg * 4;
    #pragma unroll
    for (int nt = 0; nt < 4; ++nt) {
        int px = y * 256 + x0 + nt * 16 + lr;
        #pragma unroll
        for (int i = 0; i < 4; ++i)
            out[(size_t)(co + i) * HW + px] = fmaxf(C[nt][i] + bias[co + i], 0.f);
    }
}

// ===================== GRU via MFMA (unchanged math; optional hT emit) ======
__global__ __launch_bounds__(128) void k_prep_gru(const float* __restrict__ ihw,
        const float* __restrict__ ihb, const float* __restrict__ hhw,
        const float* __restrict__ hhb, short* __restrict__ w2, float* __restrict__ bias) {
    int k = threadIdx.x;      // 0..127
    int r = blockIdx.x;       // 0..255
    int g = r >> 6, co = r & 63;
    float v = 0.f;
    if (g == 0)      v = (k < 64) ? ihw[co * 64 + k]         : hhw[co * 64 + k - 64];
    else if (g == 1) v = (k < 64) ? ihw[(64 + co) * 64 + k]  : hhw[(64 + co) * 64 + k - 64];
    else if (g == 2) v = (k < 64) ? ihw[(128 + co) * 64 + k] : 0.f;
    else             v = (k < 64) ? 0.f : hhw[(128 + co) * 64 + k - 64];
    w2[r * 128 + k] = f2bf(v);
    if (k == 0) {
        float b = (g == 0) ? ihb[co] + hhb[co]
                : (g == 1) ? ihb[64 + co] + hhb[64 + co]
                : (g == 2) ? ihb[128 + co] : hhb[128 + co];
        bias[r] = b;
    }
}

__global__ __launch_bounds__(256, 2) void gru_mfma(const float* __restrict__ xin,
        const float* __restrict__ h, const short* __restrict__ w2,
        const float* __restrict__ bias, float* __restrict__ hout,
        short* __restrict__ hT) {
    int wv = threadIdx.x >> 6, l = threadIdx.x & 63;
    int lr = l & 15, lg = l >> 4;
    int px0 = blockIdx.x * 64;

    bf16x8 A0[4], A1[4], A2[2], A3[2];
    {
        const short* w0 = w2 + (0   + wv * 16 + lr) * 128 + lg * 8;
        const short* w1 = w2 + (64  + wv * 16 + lr) * 128 + lg * 8;
        const short* w2p = w2 + (128 + wv * 16 + lr) * 128 + lg * 8;
        const short* w3 = w2 + (192 + wv * 16 + lr) * 128 + lg * 8;
        #pragma unroll
        for (int kt = 0; kt < 4; ++kt) {
            A0[kt] = *(const bf16x8*)(w0 + kt * 32);
            A1[kt] = *(const bf16x8*)(w1 + kt * 32);
        }
        A2[0] = *(const bf16x8*)(w2p);          A2[1] = *(const bf16x8*)(w2p + 32);
        A3[0] = *(const bf16x8*)(w3 + 64);      A3[1] = *(const bf16x8*)(w3 + 96);
    }

    f32x4 C0[4], C1[4], C2[4], C3[4];
    #pragma unroll
    for (int nt = 0; nt < 4; ++nt) {
        C0[nt] = (f32x4){0.f, 0.f, 0.f, 0.f};
        C1[nt] = (f32x4){0.f, 0.f, 0.f, 0.f};
        C2[nt] = (f32x4){0.f, 0.f, 0.f, 0.f};
        C3[nt] = (f32x4){0.f, 0.f, 0.f, 0.f};
    }

    #pragma unroll
    for (int nt = 0; nt < 4; ++nt) {
        int px = px0 + nt * 16 + lr;
        bf16x8 B[4];
        #pragma unroll
        for (int kt = 0; kt < 4; ++kt) {
            const float* src = (kt < 2) ? xin + (size_t)(kt * 32 + lg * 8) * HW + px
                                        : h   + (size_t)((kt - 2) * 32 + lg * 8) * HW + px;
            #pragma unroll
            for (int j = 0; j < 8; ++j) B[kt][j] = f2bf(src[(size_t)j * HW]);
        }
        #pragma unroll
        for (int kt = 0; kt < 4; ++kt) {
            C0[nt] = __builtin_amdgcn_mfma_f32_16x16x32_bf16(A0[kt], B[kt], C0[nt], 0, 0, 0);
            C1[nt] = __builtin_amdgcn_mfma_f32_16x16x32_bf16(A1[kt], B[kt], C1[nt], 0, 0, 0);
        }
        C2[nt] = __builtin_amdgcn_mfma_f32_16x16x32_bf16(A2[0], B[0], C2[nt], 0, 0, 0);
        C2[nt] = __builtin_amdgcn_mfma_f32_16x16x32_bf16(A2[1], B[1], C2[nt], 0, 0, 0);
        C3[nt] = __builtin_amdgcn_mfma_f32_16x16x32_bf16(A3[0], B[2], C3[nt], 0, 0, 0);
        C3[nt] = __builtin_amdgcn_mfma_f32_16x16x32_bf16(A3[1], B[3], C3[nt], 0, 0, 0);
    }

    int co = wv * 16 + lg * 4;
    float br[4], bz[4], bin_[4], bhn[4];
    #pragma unroll
    for (int i = 0; i < 4; ++i) {
        br[i]   = bias[co + i];
        bz[i]   = bias[64 + co + i];
        bin_[i] = bias[128 + co + i];
        bhn[i]  = bias[192 + co + i];
    }
    #pragma unroll
    for (int nt = 0; nt < 4; ++nt) {
        int px = px0 + nt * 16 + lr;
        #pragma unroll
        for (int i = 0; i < 4; ++i) {
            float r = 1.0f / (1.0f + expf(-(C0[nt][i] + br[i])));
            float z = 1.0f / (1.0f + expf(-(C1[nt][i] + bz[i])));
            float nn = tanhf(C2[nt][i] + bin_[i] + r * (C3[nt][i] + bhn[i]));
            float ho = h[(size_t)(co + i) * HW + px];
            float hv = (1.0f - z) * nn + z * ho;
            hout[(size_t)(co + i) * HW + px] = hv;
            if (hT) hT[(size_t)px * 64 + co + i] = f2bf(hv);
        }
    }
}

// final conv 64->2, 3x3, pad 1, no bias; eta += (d0, d1).
__global__ __launch_bounds__(256, 4) void final_conv_eta(const float* __restrict__ h2,
        const float* __restrict__ w, c32* __restrict__ eta) {
    int x = threadIdx.x, y = blockIdx.x;
    float a0 = 0.f, a1 = 0.f;
    for (int ci = 0; ci < 64; ++ci) {
        float v[9];
        #pragma unroll
        for (int ky = 0; ky < 3; ++ky) {
            int yy = y + ky - 1;
            bool yok = (unsigned)yy < 256u;
            const float* row = h2 + ci * HW + yy * 256;
            #pragma unroll
            for (int kx = 0; kx < 3; ++kx) {
                int xx = x + kx - 1;
                v[ky * 3 + kx] = (yok && (unsigned)xx < 256u) ? row[xx] : 0.f;
            }
        }
        const float* wc = w + ci * 9;
        #pragma unroll
        for (int t = 0; t < 9; ++t) {
            a0 += v[t] * wc[t];
            a1 += v[t] * wc[576 + t];
        }
    }
    int p = y * 256 + x;
    c32 e = eta[p];
    eta[p] = make_float2(e.x + a0, e.y + a1);
}

// ===================== host orchestration =====================
extern "C" void kernel_launch(void* const* d_in, const int* in_sizes, int n_in,
                              void* d_out, int out_size, void* d_ws, size_t ws_size,
                              hipStream_t stream) {
    const c32* pred   = (const c32*)d_in[0];
    const c32* ksp    = (const c32*)d_in[1];
    const c32* sense  = (const c32*)d_in[2];
    const int* mask   = (const int*)d_in[3];
    const float* c1w  = (const float*)d_in[4];
    const float* c1b  = (const float*)d_in[5];
    const float* g1iw = (const float*)d_in[6];
    const float* g1ib = (const float*)d_in[7];
    const float* g1hw = (const float*)d_in[8];
    const float* g1hb = (const float*)d_in[9];
    const float* c2w  = (const float*)d_in[10];
    const float* c2b  = (const float*)d_in[11];
    const float* g2iw = (const float*)d_in[12];
    const float* g2ib = (const float*)d_in[13];
    const float* g2hw = (const float*)d_in[14];
    const float* g2hb = (const float*)d_in[15];
    const float* fw   = (const float*)d_in[16];
    const float* dcw  = (const float*)d_in[17];

    float* w0 = (float*)d_ws;
    c32* base = (c32*)w0;                  // NC*HW complex
    c32* Fk   = base + NC * HW;            // NC*HW complex
    c32* tmp  = Fk + NC * HW;              // NC*HW complex
    c32* eta  = tmp + NC * HW;             // HW complex
    float* g  = (float*)(eta + HW);        // 4*HW
    float* x1 = g + 4 * HW;                // NF*HW
    float* h1a = x1 + NF * HW;
    float* h1b = h1a + NF * HW;
    float* h2a = h1b + NF * HW;
    float* h2b = h2a + NF * HW;
    short* w2a  = (short*)(h2b + NF * HW); // 256*128 bf16
    short* w2b  = w2a + 256 * 128;
    float* biasA = (float*)(w2b + 256 * 128);
    float* biasB = biasA + 256;
    short* h1T  = (short*)(biasB + 256);   // HW*64 bf16 (transposed gru1 out)
    short* wAc2 = h1T + (size_t)HW * 64;   // 9*64*64 bf16

    (void)hipMemsetAsync(h1a, 0, (size_t)NF * HW * 4, stream);
    (void)hipMemsetAsync(h2a, 0, (size_t)NF * HW * 4, stream);

    dim3 B(256);
    const int gCHW = NC * HW / 256;   // 3072
    const int gHW  = HW / 256;        // 256
    const int gROW = NC * 256 / 4;    // 768
    dim3 gCOL(64, NC);
    dim3 gC16(256, 4);
    const int gGRU = HW / 64;         // 1024 blocks

    // weight prep (once per call)
    k_prep_gru<<<256, 128, 0, stream>>>(g1iw, g1ib, g1hw, g1hb, w2a, biasA);
    k_prep_gru<<<256, 128, 0, stream>>>(g2iw, g2ib, g2hw, g2hb, w2b, biasB);
    k_prep_c2<<<144, 256, 0, stream>>>(c2w, wAc2);

    // eta0 = sum_c ifft2c(pred_c) * conj(sense_c)
    k_pre<<<gCHW, B, 0, stream>>>(pred, tmp);
    fft_rows<<<gROW, B, 0, stream>>>(tmp, -1.0f);
    fft_cols<<<gCOL, B, 0, stream>>>(tmp, -1.0f);
    k_combine_eta0<<<gHW, B, 0, stream>>>(tmp, sense, eta);

    k_base<<<gCHW, B, 0, stream>>>(ksp, pred, mask, dcw, base);

    // F_0: G = FFT2u(S*(eta*sense))
    k_expand<<<gCHW, B, 0, stream>>>(eta, sense, Fk);
    fft_rows<<<gROW, B, 0, stream>>>(Fk, 1.0f);
    fft_cols<<<gCOL, B, 0, stream>>>(Fk, 1.0f);

    float* h1c = h1a; float* h1n = h1b;
    float* h2c = h2a; float* h2n = h2b;
    c32* outp = (c32*)d_out;

    for (int t = 0; t < NT; ++t) {
        // gradient from cached F_{t-1}
        k_resid<<<gCHW, B, 0, stream>>>(Fk, ksp, mask, tmp);
        fft_rows<<<gROW, B, 0, stream>>>(tmp, -1.0f);
        fft_cols<<<gCOL, B, 0, stream>>>(tmp, -1.0f);
        k_grad_g<<<gHW, B, 0, stream>>>(tmp, sense, eta, g);

        // network
        conv1_relu<<<gC16, B, 0, stream>>>(g, c1w, c1b, x1);
        gru_mfma<<<gGRU, B, 0, stream>>>(x1, h1c, w2a, biasA, h1n, h1T);
        { float* s = h1c; h1c = h1n; h1n = s; }
        conv2_mfma<<<gGRU, B, 0, stream>>>(h1T, wAc2, c2b, x1);
        gru_mfma<<<gGRU, B, 0, stream>>>(x1, h2c, w2b, biasB, h2n, nullptr);
        { float* s = h2c; h2c = h2n; h2n = s; }
        final_conv_eta<<<256, B, 0, stream>>>(h2c, fw, eta);

        // F_t for this step's output (and next step's gradient)
        k_expand<<<gCHW, B, 0, stream>>>(eta, sense, Fk);
        fft_rows<<<gROW, B, 0, stream>>>(Fk, 1.0f);
        fft_cols<<<gCOL, B, 0, stream>>>(Fk, 1.0f);
        k_out<<<gCHW, B, 0, stream>>>(base, Fk, outp + (size_t)t * NC * HW);
    }
}

// Round 7
// 1520.675 us; speedup vs baseline: 3.0924x; 1.2672x over previous
//
#include <hip/hip_runtime.h>

#define HW 65536
#define NC 12
#define NF 64
#define NT 8

typedef float2 c32;
typedef __attribute__((ext_vector_type(8))) short bf16x8;   // 8 bf16 = 4 VGPR
typedef __attribute__((ext_vector_type(4))) float f32x4;    // MFMA C/D

__device__ __forceinline__ float ssign(int p) {
    return ((p ^ (p >> 8)) & 1) ? -1.0f : 1.0f;
}

__device__ __forceinline__ short f2bf(float f) {   // RNE float->bf16
    union { float f; unsigned u; } v; v.f = f;
    unsigned r = (v.u + 0x7FFFu + ((v.u >> 16) & 1u)) >> 16;
    return (short)r;
}

// ===================== 256-point radix-2 DIT FFT in LDS =====================
__device__ __forceinline__ void fft256_stages(c32* X, const c32* tw, int j, float conjf) {
    #pragma unroll
    for (int s = 1; s <= 8; ++s) {
        const int half = 1 << (s - 1);
        #pragma unroll
        for (int b = 0; b < 2; ++b) {
            int idx = j + (b << 6);
            int grp = idx >> (s - 1);
            int pos = idx & (half - 1);
            int i0 = (grp << s) + pos;
            int i1 = i0 + half;
            c32 w = tw[pos << (8 - s)];
            float wy = conjf * w.y;
            c32 a = X[i0], cc = X[i1];
            c32 t = make_float2(w.x * cc.x - wy * cc.y, w.x * cc.y + wy * cc.x);
            X[i0] = make_float2(a.x + t.x, a.y + t.y);
            X[i1] = make_float2(a.x - t.x, a.y - t.y);
        }
        __syncthreads();
    }
}

__device__ __forceinline__ void build_tw(c32* tw, int tid) {
    if (tid < 128) {
        float a = -3.14159265358979323846f * (float)tid * (1.0f / 128.0f);
        float sv, cv;
        sincosf(a, &sv, &cv);
        tw[tid] = make_float2(cv, sv);
    }
}

__global__ __launch_bounds__(256) void fft_rows(c32* __restrict__ buf, float conjf) {
    __shared__ c32 lds[4][256];
    __shared__ c32 tw[128];
    int tid = threadIdx.x;
    build_tw(tw, tid);
    int wid = tid >> 6, j = tid & 63;
    c32* rp = buf + (size_t)(blockIdx.x * 4 + wid) * 256;
    c32* X = lds[wid];
    #pragma unroll
    for (int e = 0; e < 4; ++e) {
        int n = (e << 6) + j;
        X[__brev((unsigned)n) >> 24] = rp[n];
    }
    __syncthreads();
    fft256_stages(X, tw, j, conjf);
    #pragma unroll
    for (int e = 0; e < 4; ++e) {
        int n = (e << 6) + j;
        rp[n] = X[n];
    }
}

__global__ __launch_bounds__(256) void fft_cols(c32* __restrict__ buf, float conjf) {
    __shared__ c32 lds[4][257];
    __shared__ c32 tw[128];
    int tid = threadIdx.x;
    build_tw(tw, tid);
    c32* ip = buf + (size_t)blockIdx.y * HW;
    int x0 = blockIdx.x * 4;
    int cl = tid & 3, yb = tid >> 2;
    #pragma unroll
    for (int e = 0; e < 4; ++e) {
        int y = yb + (e << 6);
        lds[cl][__brev((unsigned)y) >> 24] = ip[y * 256 + x0 + cl];
    }
    __syncthreads();
    int col = tid >> 6, j = tid & 63;
    fft256_stages(&lds[col][0], tw, j, conjf);
    #pragma unroll
    for (int e = 0; e < 4; ++e) {
        int y = yb + (e << 6);
        ip[y * 256 + x0 + cl] = lds[cl][y];
    }
}

// ===================== pointwise kernels =====================
__global__ __launch_bounds__(256) void k_pre(const c32* __restrict__ pred, c32* __restrict__ tmp) {
    int i = blockIdx.x * 256 + threadIdx.x;
    int p = i & (HW - 1);
    float s = ssign(p);
    c32 v = pred[i];
    tmp[i] = make_float2(s * v.x, s * v.y);
}

__global__ __launch_bounds__(256) void k_combine_eta0(const c32* __restrict__ tmp,
        const c32* __restrict__ sense, c32* __restrict__ eta) {
    int p = blockIdx.x * 256 + threadIdx.x;
    float ax = 0.f, ay = 0.f;
    for (int c = 0; c < NC; ++c) {
        c32 t = tmp[c * HW + p], s = sense[c * HW + p];
        ax += t.x * s.x + t.y * s.y;
        ay += t.y * s.x - t.x * s.y;
    }
    float sc = ssign(p) * (1.0f / 256.0f);
    eta[p] = make_float2(ax * sc, ay * sc);
}

__global__ __launch_bounds__(256) void k_base(const c32* __restrict__ ksp,
        const c32* __restrict__ pred, const int* __restrict__ mask,
        const float* __restrict__ dcw, c32* __restrict__ base) {
    int i = blockIdx.x * 256 + threadIdx.x;
    int p = i & (HW - 1);
    c32 k = ksp[i];
    c32 o = k;
    if (mask[p]) {
        float w = dcw[0];
        c32 pr = pred[i];
        o.x -= (pr.x - k.x) * w;
        o.y -= (pr.y - k.y) * w;
    }
    base[i] = o;
}

__global__ __launch_bounds__(256) void k_expand(const c32* __restrict__ eta,
        const c32* __restrict__ sense, c32* __restrict__ Fk) {
    int i = blockIdx.x * 256 + threadIdx.x;
    int p = i & (HW - 1);
    float s = ssign(p);
    c32 e = eta[p], sn = sense[i];
    Fk[i] = make_float2(s * (e.x * sn.x - e.y * sn.y), s * (e.x * sn.y + e.y * sn.x));
}

__global__ __launch_bounds__(256) void k_resid(const c32* __restrict__ Fk,
        const c32* __restrict__ ksp, const int* __restrict__ mask, c32* __restrict__ tmp) {
    int i = blockIdx.x * 256 + threadIdx.x;
    int p = i & (HW - 1);
    if (!mask[p]) { tmp[i] = make_float2(0.f, 0.f); return; }
    float s = ssign(p);
    c32 g = Fk[i], k = ksp[i];
    tmp[i] = make_float2(g.x * (1.0f / 256.0f) - s * k.x,
                         g.y * (1.0f / 256.0f) - s * k.y);
}

// grad+g: emit conv1 input directly as transposed bf16 gT[px][4]
__global__ __launch_bounds__(256) void k_grad_g(const c32* __restrict__ tmp,
        const c32* __restrict__ sense, const c32* __restrict__ eta,
        short* __restrict__ gT) {
    int p = blockIdx.x * 256 + threadIdx.x;
    float ax = 0.f, ay = 0.f;
    for (int c = 0; c < NC; ++c) {
        c32 t = tmp[c * HW + p], s = sense[c * HW + p];
        ax += t.x * s.x + t.y * s.y;
        ay += t.y * s.x - t.x * s.y;
    }
    float sc = ssign(p) * (1.0f / 256.0f);
    c32 e = eta[p];
    ushort4 o;
    o.x = (unsigned short)f2bf(e.x);
    o.y = (unsigned short)f2bf(e.y);
    o.z = (unsigned short)f2bf(ax * sc);
    o.w = (unsigned short)f2bf(ay * sc);
    ((ushort4*)gT)[p] = o;
}

__global__ __launch_bounds__(256) void k_out(const c32* __restrict__ base,
        const c32* __restrict__ Fk, c32* __restrict__ outp) {
    int i = blockIdx.x * 256 + threadIdx.x;
    int p = i & (HW - 1);
    float sc = ssign(p) * (1.0f / 256.0f);
    c32 g = Fk[i], b = base[i];
    outp[i] = make_float2(b.x - sc * g.x, b.y - sc * g.y);
}

// ===================== weight prep kernels =====================
// conv1 A: wA1[co][k], k = tap*4+ci (tap<25), pad k>=100 with zeros.
__global__ __launch_bounds__(256) void k_prep_c1(const float* __restrict__ w,
        short* __restrict__ wA) {
    int i = blockIdx.x * 256 + threadIdx.x;    // 64*128 = 8192
    int co = i >> 7, k = i & 127;
    int tap = k >> 2, ci = k & 3;
    float v = (tap < 25) ? w[co * 100 + ci * 25 + tap] : 0.f;
    wA[i] = f2bf(v);
}

// conv2 A: wA[tap][co][ci] from OIHW c2w[co][ci][ky][kx]
__global__ __launch_bounds__(256) void k_prep_c2(const float* __restrict__ w,
        short* __restrict__ wA) {
    int i = blockIdx.x * 256 + threadIdx.x;     // 36864 total
    int tap = i >> 12, co = (i >> 6) & 63, ci = i & 63;
    wA[i] = f2bf(w[co * 576 + ci * 9 + tap]);
}

// final A: wA[tap][16 rows][64 ci], rows 0,1 = out channels, rest zero.
__global__ __launch_bounds__(256) void k_prep_cf(const float* __restrict__ w,
        short* __restrict__ wA) {
    int i = blockIdx.x * 256 + threadIdx.x;    // 9*16*64 = 9216
    int tap = i >> 10, r = (i >> 6) & 15, ci = i & 63;
    float v = (r < 2) ? w[r * 576 + ci * 9 + tap] : 0.f;
    wA[i] = f2bf(v);
}

__global__ __launch_bounds__(128) void k_prep_gru(const float* __restrict__ ihw,
        const float* __restrict__ ihb, const float* __restrict__ hhw,
        const float* __restrict__ hhb, short* __restrict__ w2, float* __restrict__ bias) {
    int k = threadIdx.x;      // 0..127
    int r = blockIdx.x;       // 0..255
    int g = r >> 6, co = r & 63;
    float v = 0.f;
    if (g == 0)      v = (k < 64) ? ihw[co * 64 + k]         : hhw[co * 64 + k - 64];
    else if (g == 1) v = (k < 64) ? ihw[(64 + co) * 64 + k]  : hhw[(64 + co) * 64 + k - 64];
    else if (g == 2) v = (k < 64) ? ihw[(128 + co) * 64 + k] : 0.f;
    else             v = (k < 64) ? 0.f : hhw[(128 + co) * 64 + k - 64];
    w2[r * 128 + k] = f2bf(v);
    if (k == 0) {
        float b = (g == 0) ? ihb[co] + hhb[co]
                : (g == 1) ? ihb[64 + co] + hhb[64 + co]
                : (g == 2) ? ihb[128 + co] : hhb[128 + co];
        bias[r] = b;
    }
}

// ===================== conv1 via MFMA =====================
// grid 1024 (y * 4 x-seg), 256 thr. Wave wv: co [16wv,16wv+16).
// B-frag: two masked 8B loads from gT (2 taps x 4 ci per lane).
__global__ __launch_bounds__(256, 2) void conv1_mfma(const short* __restrict__ gT,
        const short* __restrict__ wA, const float* __restrict__ bias,
        float* __restrict__ out) {
    int wv = threadIdx.x >> 6, l = threadIdx.x & 63;
    int lr = l & 15, lg = l >> 4;
    int y = blockIdx.x >> 2;
    int x0 = (blockIdx.x & 3) << 6;

    bf16x8 A[4];
    const short* pA = wA + (size_t)(wv * 16 + lr) * 128 + lg * 8;
    #pragma unroll
    for (int kt = 0; kt < 4; ++kt) A[kt] = *(const bf16x8*)(pA + kt * 32);

    f32x4 C[4];
    #pragma unroll
    for (int nt = 0; nt < 4; ++nt) {
        C[nt] = (f32x4){0.f, 0.f, 0.f, 0.f};
        int x = x0 + nt * 16 + lr;
        #pragma unroll
        for (int kt = 0; kt < 4; ++kt) {
            int t0 = kt * 8 + lg * 2;      // first tap of this lane's 8 k's
            bf16x8 B;
            #pragma unroll
            for (int half = 0; half < 2; ++half) {
                int tap = t0 + half;
                int dy = tap / 5 - 2, dx = tap % 5 - 2;
                int yy = y + dy, xx = x + dx;
                bool ok = (tap < 25) && ((unsigned)yy < 256u) && ((unsigned)xx < 256u);
                ushort4 v = make_ushort4(0, 0, 0, 0);
                if (ok) v = *(const ushort4*)(gT + ((size_t)(yy * 256 + xx) << 2));
                B[half * 4 + 0] = (short)v.x;
                B[half * 4 + 1] = (short)v.y;
                B[half * 4 + 2] = (short)v.z;
                B[half * 4 + 3] = (short)v.w;
            }
            C[nt] = __builtin_amdgcn_mfma_f32_16x16x32_bf16(A[kt], B, C[nt], 0, 0, 0);
        }
    }
    int co = wv * 16 + lg * 4;
    #pragma unroll
    for (int nt = 0; nt < 4; ++nt) {
        int px = y * 256 + x0 + nt * 16 + lr;
        #pragma unroll
        for (int i = 0; i < 4; ++i)
            out[(size_t)(co + i) * HW + px] = fmaxf(C[nt][i] + bias[co + i], 0.f);
    }
}

// ===================== conv2 via MFMA =====================
__global__ __launch_bounds__(256, 2) void conv2_mfma(const short* __restrict__ hT,
        const short* __restrict__ wA, const float* __restrict__ bias,
        float* __restrict__ out) {
    int wv = threadIdx.x >> 6, l = threadIdx.x & 63;
    int lr = l & 15, lg = l >> 4;
    int y = blockIdx.x >> 2;
    int x0 = (blockIdx.x & 3) << 6;

    f32x4 C[4];
    #pragma unroll
    for (int nt = 0; nt < 4; ++nt) C[nt] = (f32x4){0.f, 0.f, 0.f, 0.f};

    #pragma unroll
    for (int tap = 0; tap < 9; ++tap) {
        const int dy = (tap / 3 - 1) * 2, dx = (tap % 3 - 1) * 2;
        int yy = y + dy;
        bool yok = (unsigned)yy < 256u;
        const short* pA = wA + (size_t)(tap * 64 + wv * 16 + lr) * 64 + lg * 8;
        bf16x8 A0 = *(const bf16x8*)(pA);
        bf16x8 A1 = *(const bf16x8*)(pA + 32);
        #pragma unroll
        for (int nt = 0; nt < 4; ++nt) {
            int xx = x0 + nt * 16 + lr + dx;
            bool ok = yok && ((unsigned)xx < 256u);
            int pcl = ok ? (yy * 256 + xx) : 0;
            const short* pB = hT + (size_t)pcl * 64 + lg * 8;
            bf16x8 B0 = {}, B1 = {};
            if (ok) {
                B0 = *(const bf16x8*)(pB);
                B1 = *(const bf16x8*)(pB + 32);
            }
            C[nt] = __builtin_amdgcn_mfma_f32_16x16x32_bf16(A0, B0, C[nt], 0, 0, 0);
            C[nt] = __builtin_amdgcn_mfma_f32_16x16x32_bf16(A1, B1, C[nt], 0, 0, 0);
        }
    }
    int co = wv * 16 + lg * 4;
    #pragma unroll
    for (int nt = 0; nt < 4; ++nt) {
        int px = y * 256 + x0 + nt * 16 + lr;
        #pragma unroll
        for (int i = 0; i < 4; ++i)
            out[(size_t)(co + i) * HW + px] = fmaxf(C[nt][i] + bias[co + i], 0.f);
    }
}

// ===================== GRU via MFMA =====================
__global__ __launch_bounds__(256, 2) void gru_mfma(const float* __restrict__ xin,
        const float* __restrict__ h, const short* __restrict__ w2,
        const float* __restrict__ bias, float* __restrict__ hout,
        short* __restrict__ hT) {
    int wv = threadIdx.x >> 6, l = threadIdx.x & 63;
    int lr = l & 15, lg = l >> 4;
    int px0 = blockIdx.x * 64;

    bf16x8 A0[4], A1[4], A2[2], A3[2];
    {
        const short* w0 = w2 + (0   + wv * 16 + lr) * 128 + lg * 8;
        const short* w1 = w2 + (64  + wv * 16 + lr) * 128 + lg * 8;
        const short* w2p = w2 + (128 + wv * 16 + lr) * 128 + lg * 8;
        const short* w3 = w2 + (192 + wv * 16 + lr) * 128 + lg * 8;
        #pragma unroll
        for (int kt = 0; kt < 4; ++kt) {
            A0[kt] = *(const bf16x8*)(w0 + kt * 32);
            A1[kt] = *(const bf16x8*)(w1 + kt * 32);
        }
        A2[0] = *(const bf16x8*)(w2p);          A2[1] = *(const bf16x8*)(w2p + 32);
        A3[0] = *(const bf16x8*)(w3 + 64);      A3[1] = *(const bf16x8*)(w3 + 96);
    }

    f32x4 C0[4], C1[4], C2[4], C3[4];
    #pragma unroll
    for (int nt = 0; nt < 4; ++nt) {
        C0[nt] = (f32x4){0.f, 0.f, 0.f, 0.f};
        C1[nt] = (f32x4){0.f, 0.f, 0.f, 0.f};
        C2[nt] = (f32x4){0.f, 0.f, 0.f, 0.f};
        C3[nt] = (f32x4){0.f, 0.f, 0.f, 0.f};
    }

    #pragma unroll
    for (int nt = 0; nt < 4; ++nt) {
        int px = px0 + nt * 16 + lr;
        bf16x8 B[4];
        #pragma unroll
        for (int kt = 0; kt < 4; ++kt) {
            const float* src = (kt < 2) ? xin + (size_t)(kt * 32 + lg * 8) * HW + px
                                        : h   + (size_t)((kt - 2) * 32 + lg * 8) * HW + px;
            #pragma unroll
            for (int j = 0; j < 8; ++j) B[kt][j] = f2bf(src[(size_t)j * HW]);
        }
        #pragma unroll
        for (int kt = 0; kt < 4; ++kt) {
            C0[nt] = __builtin_amdgcn_mfma_f32_16x16x32_bf16(A0[kt], B[kt], C0[nt], 0, 0, 0);
            C1[nt] = __builtin_amdgcn_mfma_f32_16x16x32_bf16(A1[kt], B[kt], C1[nt], 0, 0, 0);
        }
        C2[nt] = __builtin_amdgcn_mfma_f32_16x16x32_bf16(A2[0], B[0], C2[nt], 0, 0, 0);
        C2[nt] = __builtin_amdgcn_mfma_f32_16x16x32_bf16(A2[1], B[1], C2[nt], 0, 0, 0);
        C3[nt] = __builtin_amdgcn_mfma_f32_16x16x32_bf16(A3[0], B[2], C3[nt], 0, 0, 0);
        C3[nt] = __builtin_amdgcn_mfma_f32_16x16x32_bf16(A3[1], B[3], C3[nt], 0, 0, 0);
    }

    int co = wv * 16 + lg * 4;
    float br[4], bz[4], bin_[4], bhn[4];
    #pragma unroll
    for (int i = 0; i < 4; ++i) {
        br[i]   = bias[co + i];
        bz[i]   = bias[64 + co + i];
        bin_[i] = bias[128 + co + i];
        bhn[i]  = bias[192 + co + i];
    }
    #pragma unroll
    for (int nt = 0; nt < 4; ++nt) {
        int px = px0 + nt * 16 + lr;
        #pragma unroll
        for (int i = 0; i < 4; ++i) {
            float r = 1.0f / (1.0f + expf(-(C0[nt][i] + br[i])));
            float z = 1.0f / (1.0f + expf(-(C1[nt][i] + bz[i])));
            float nn = tanhf(C2[nt][i] + bin_[i] + r * (C3[nt][i] + bhn[i]));
            float ho = h[(size_t)(co + i) * HW + px];
            float hv = (1.0f - z) * nn + z * ho;
            hout[(size_t)(co + i) * HW + px] = hv;
            if (hT) hT[(size_t)px * 64 + co + i] = f2bf(hv);
        }
    }
}

// ===================== final conv via MFMA =====================
// grid 1024 blocks, 256 thr; wave wv handles nt=wv (16 px). M=16 (rows 0,1 real).
__global__ __launch_bounds__(256, 2) void final_mfma(const short* __restrict__ hT,
        const short* __restrict__ wA, c32* __restrict__ eta) {
    int wv = threadIdx.x >> 6, l = threadIdx.x & 63;
    int lr = l & 15, lg = l >> 4;
    int y = blockIdx.x >> 2;
    int x0 = (blockIdx.x & 3) << 6;
    int x = x0 + wv * 16 + lr;

    f32x4 C = (f32x4){0.f, 0.f, 0.f, 0.f};
    #pragma unroll
    for (int tap = 0; tap < 9; ++tap) {
        int dy = tap / 3 - 1, dx = tap % 3 - 1;
        int yy = y + dy, xx = x + dx;
        bool ok = ((unsigned)yy < 256u) && ((unsigned)xx < 256u);
        const short* pA = wA + (size_t)(tap * 16 + lr) * 64 + lg * 8;
        bf16x8 A0 = *(const bf16x8*)(pA);
        bf16x8 A1 = *(const bf16x8*)(pA + 32);
        int pcl = ok ? (yy * 256 + xx) : 0;
        const short* pB = hT + ((size_t)pcl << 6) + lg * 8;
        bf16x8 B0 = {}, B1 = {};
        if (ok) {
            B0 = *(const bf16x8*)(pB);
            B1 = *(const bf16x8*)(pB + 32);
        }
        C = __builtin_amdgcn_mfma_f32_16x16x32_bf16(A0, B0, C, 0, 0, 0);
        C = __builtin_amdgcn_mfma_f32_16x16x32_bf16(A1, B1, C, 0, 0, 0);
    }
    if (lg == 0) {
        int px = y * 256 + x;
        c32 e = eta[px];
        eta[px] = make_float2(e.x + C[0], e.y + C[1]);
    }
}

// ===================== host orchestration =====================
extern "C" void kernel_launch(void* const* d_in, const int* in_sizes, int n_in,
                              void* d_out, int out_size, void* d_ws, size_t ws_size,
                              hipStream_t stream) {
    const c32* pred   = (const c32*)d_in[0];
    const c32* ksp    = (const c32*)d_in[1];
    const c32* sense  = (const c32*)d_in[2];
    const int* mask   = (const int*)d_in[3];
    const float* c1w  = (const float*)d_in[4];
    const float* c1b  = (const float*)d_in[5];
    const float* g1iw = (const float*)d_in[6];
    const float* g1ib = (const float*)d_in[7];
    const float* g1hw = (const float*)d_in[8];
    const float* g1hb = (const float*)d_in[9];
    const float* c2w  = (const float*)d_in[10];
    const float* c2b  = (const float*)d_in[11];
    const float* g2iw = (const float*)d_in[12];
    const float* g2ib = (const float*)d_in[13];
    const float* g2hw = (const float*)d_in[14];
    const float* g2hb = (const float*)d_in[15];
    const float* fw   = (const float*)d_in[16];
    const float* dcw  = (const float*)d_in[17];

    float* w0 = (float*)d_ws;
    c32* base = (c32*)w0;                  // NC*HW complex
    c32* Fk   = base + NC * HW;            // NC*HW complex
    c32* tmp  = Fk + NC * HW;              // NC*HW complex
    c32* eta  = tmp + NC * HW;             // HW complex
    short* gT = (short*)(eta + HW);        // HW*4 bf16 (conv1 input, transposed)
    float* x1 = (float*)(gT + (size_t)HW * 4);  // NF*HW
    float* h1a = x1 + NF * HW;
    float* h1b = h1a + NF * HW;
    float* h2a = h1b + NF * HW;
    float* h2b = h2a + NF * HW;
    short* w2a  = (short*)(h2b + NF * HW); // 256*128 bf16
    short* w2b  = w2a + 256 * 128;
    float* biasA = (float*)(w2b + 256 * 128);
    float* biasB = biasA + 256;
    short* h1T  = (short*)(biasB + 256);   // HW*64 bf16
    short* h2T  = h1T + (size_t)HW * 64;   // HW*64 bf16
    short* wAc2 = h2T + (size_t)HW * 64;   // 9*64*64 bf16
    short* wAc1 = wAc2 + 9 * 64 * 64;      // 64*128 bf16
    short* wAcf = wAc1 + 64 * 128;         // 9*16*64 bf16

    (void)hipMemsetAsync(h1a, 0, (size_t)NF * HW * 4, stream);
    (void)hipMemsetAsync(h2a, 0, (size_t)NF * HW * 4, stream);

    dim3 B(256);
    const int gCHW = NC * HW / 256;   // 3072
    const int gHW  = HW / 256;        // 256
    const int gROW = NC * 256 / 4;    // 768
    dim3 gCOL(64, NC);
    const int gGRU = HW / 64;         // 1024 blocks

    // weight prep (once per call)
    k_prep_gru<<<256, 128, 0, stream>>>(g1iw, g1ib, g1hw, g1hb, w2a, biasA);
    k_prep_gru<<<256, 128, 0, stream>>>(g2iw, g2ib, g2hw, g2hb, w2b, biasB);
    k_prep_c2<<<144, 256, 0, stream>>>(c2w, wAc2);
    k_prep_c1<<<32, 256, 0, stream>>>(c1w, wAc1);
    k_prep_cf<<<36, 256, 0, stream>>>(fw, wAcf);

    // eta0 = sum_c ifft2c(pred_c) * conj(sense_c)
    k_pre<<<gCHW, B, 0, stream>>>(pred, tmp);
    fft_rows<<<gROW, B, 0, stream>>>(tmp, -1.0f);
    fft_cols<<<gCOL, B, 0, stream>>>(tmp, -1.0f);
    k_combine_eta0<<<gHW, B, 0, stream>>>(tmp, sense, eta);

    k_base<<<gCHW, B, 0, stream>>>(ksp, pred, mask, dcw, base);

    // F_0: G = FFT2u(S*(eta*sense))
    k_expand<<<gCHW, B, 0, stream>>>(eta, sense, Fk);
    fft_rows<<<gROW, B, 0, stream>>>(Fk, 1.0f);
    fft_cols<<<gCOL, B, 0, stream>>>(Fk, 1.0f);

    float* h1c = h1a; float* h1n = h1b;
    float* h2c = h2a; float* h2n = h2b;
    c32* outp = (c32*)d_out;

    for (int t = 0; t < NT; ++t) {
        // gradient from cached F_{t-1}
        k_resid<<<gCHW, B, 0, stream>>>(Fk, ksp, mask, tmp);
        fft_rows<<<gROW, B, 0, stream>>>(tmp, -1.0f);
        fft_cols<<<gCOL, B, 0, stream>>>(tmp, -1.0f);
        k_grad_g<<<gHW, B, 0, stream>>>(tmp, sense, eta, gT);

        // network (all MFMA now)
        conv1_mfma<<<gGRU, B, 0, stream>>>(gT, wAc1, c1b, x1);
        gru_mfma<<<gGRU, B, 0, stream>>>(x1, h1c, w2a, biasA, h1n, h1T);
        { float* s = h1c; h1c = h1n; h1n = s; }
        conv2_mfma<<<gGRU, B, 0, stream>>>(h1T, wAc2, c2b, x1);
        gru_mfma<<<gGRU, B, 0, stream>>>(x1, h2c, w2b, biasB, h2n, h2T);
        { float* s = h2c; h2c = h2n; h2n = s; }
        final_mfma<<<gGRU, B, 0, stream>>>(h2T, wAcf, eta);

        // F_t for this step's output (and next step's gradient)
        k_expand<<<gCHW, B, 0, stream>>>(eta, sense, Fk);
        fft_rows<<<gROW, B, 0, stream>>>(Fk, 1.0f);
        fft_cols<<<gCOL, B, 0, stream>>>(Fk, 1.0f);
        k_out<<<gCHW, B, 0, stream>>>(base, Fk, outp + (size_t)t * NC * HW);
    }
}

// Round 8
// 1332.843 us; speedup vs baseline: 3.5282x; 1.1409x over previous
//
#include <hip/hip_runtime.h>

#define HW 65536
#define NC 12
#define NF 64
#define NT 8

typedef float2 c32;
typedef __attribute__((ext_vector_type(8))) short bf16x8;   // 8 bf16 = 4 VGPR
typedef __attribute__((ext_vector_type(4))) float f32x4;    // MFMA C/D

__device__ __forceinline__ float ssign(int p) {
    return ((p ^ (p >> 8)) & 1) ? -1.0f : 1.0f;
}

__device__ __forceinline__ short f2bf(float f) {   // RNE float->bf16
    union { float f; unsigned u; } v; v.f = f;
    unsigned r = (v.u + 0x7FFFu + ((v.u >> 16) & 1u)) >> 16;
    return (short)r;
}

// ===================== 256-point radix-2 DIT FFT in LDS =====================
__device__ __forceinline__ void fft256_stages(c32* X, const c32* tw, int j, float conjf) {
    #pragma unroll
    for (int s = 1; s <= 8; ++s) {
        const int half = 1 << (s - 1);
        #pragma unroll
        for (int b = 0; b < 2; ++b) {
            int idx = j + (b << 6);
            int grp = idx >> (s - 1);
            int pos = idx & (half - 1);
            int i0 = (grp << s) + pos;
            int i1 = i0 + half;
            c32 w = tw[pos << (8 - s)];
            float wy = conjf * w.y;
            c32 a = X[i0], cc = X[i1];
            c32 t = make_float2(w.x * cc.x - wy * cc.y, w.x * cc.y + wy * cc.x);
            X[i0] = make_float2(a.x + t.x, a.y + t.y);
            X[i1] = make_float2(a.x - t.x, a.y - t.y);
        }
        __syncthreads();
    }
}

__device__ __forceinline__ void build_tw(c32* tw, int tid) {
    if (tid < 128) {
        float a = -3.14159265358979323846f * (float)tid * (1.0f / 128.0f);
        float sv, cv;
        sincosf(a, &sv, &cv);
        tw[tid] = make_float2(cv, sv);
    }
}

// Plain in-place row FFT. grid 768, 256 thr.
__global__ __launch_bounds__(256) void fft_rows(c32* __restrict__ buf, float conjf) {
    __shared__ c32 lds[4][256];
    __shared__ c32 tw[128];
    int tid = threadIdx.x;
    build_tw(tw, tid);
    int wid = tid >> 6, j = tid & 63;
    c32* rp = buf + (size_t)(blockIdx.x * 4 + wid) * 256;
    c32* X = lds[wid];
    #pragma unroll
    for (int e = 0; e < 4; ++e) {
        int n = (e << 6) + j;
        X[__brev((unsigned)n) >> 24] = rp[n];
    }
    __syncthreads();
    fft256_stages(X, tw, j, conjf);
    #pragma unroll
    for (int e = 0; e < 4; ++e) {
        int n = (e << 6) + j;
        rp[n] = X[n];
    }
}

// Row inverse FFT with fused load: X = S * pred. grid 768.
__global__ __launch_bounds__(256) void fft_rows_pre(c32* __restrict__ buf,
        const c32* __restrict__ pred) {
    __shared__ c32 lds[4][256];
    __shared__ c32 tw[128];
    int tid = threadIdx.x;
    build_tw(tw, tid);
    int wid = tid >> 6, j = tid & 63;
    int r = blockIdx.x * 4 + wid;
    int coil = r >> 8, y = r & 255;
    c32* rp = buf + (size_t)r * 256;
    c32* X = lds[wid];
    #pragma unroll
    for (int e = 0; e < 4; ++e) {
        int n = (e << 6) + j;
        float s = ((n + y) & 1) ? -1.0f : 1.0f;
        c32 pv = pred[(size_t)coil * HW + y * 256 + n];
        X[__brev((unsigned)n) >> 24] = make_float2(s * pv.x, s * pv.y);
    }
    __syncthreads();
    fft256_stages(X, tw, j, -1.0f);
    #pragma unroll
    for (int e = 0; e < 4; ++e) {
        int n = (e << 6) + j;
        rp[n] = X[n];
    }
}

// Row forward FFT with fused load: X = S * eta * sense. grid 768.
__global__ __launch_bounds__(256) void fft_rows_exp(c32* __restrict__ buf,
        const c32* __restrict__ eta, const c32* __restrict__ sense) {
    __shared__ c32 lds[4][256];
    __shared__ c32 tw[128];
    int tid = threadIdx.x;
    build_tw(tw, tid);
    int wid = tid >> 6, j = tid & 63;
    int r = blockIdx.x * 4 + wid;
    int coil = r >> 8, y = r & 255;
    c32* rp = buf + (size_t)r * 256;
    c32* X = lds[wid];
    #pragma unroll
    for (int e = 0; e < 4; ++e) {
        int n = (e << 6) + j;
        float s = ((n + y) & 1) ? -1.0f : 1.0f;
        c32 ev = eta[y * 256 + n];
        c32 sn = sense[(size_t)coil * HW + y * 256 + n];
        X[__brev((unsigned)n) >> 24] =
            make_float2(s * (ev.x * sn.x - ev.y * sn.y),
                        s * (ev.x * sn.y + ev.y * sn.x));
    }
    __syncthreads();
    fft256_stages(X, tw, j, 1.0f);
    #pragma unroll
    for (int e = 0; e < 4; ++e) {
        int n = (e << 6) + j;
        rp[n] = X[n];
    }
}

// Plain in-place col FFT. grid (64, NC).
__global__ __launch_bounds__(256) void fft_cols(c32* __restrict__ buf, float conjf) {
    __shared__ c32 lds[4][257];
    __shared__ c32 tw[128];
    int tid = threadIdx.x;
    build_tw(tw, tid);
    c32* ip = buf + (size_t)blockIdx.y * HW;
    int x0 = blockIdx.x * 4;
    int cl = tid & 3, yb = tid >> 2;
    #pragma unroll
    for (int e = 0; e < 4; ++e) {
        int y = yb + (e << 6);
        lds[cl][__brev((unsigned)y) >> 24] = ip[y * 256 + x0 + cl];
    }
    __syncthreads();
    int col = tid >> 6, j = tid & 63;
    fft256_stages(&lds[col][0], tw, j, conjf);
    #pragma unroll
    for (int e = 0; e < 4; ++e) {
        int y = yb + (e << 6);
        ip[y * 256 + x0 + cl] = lds[cl][y];
    }
}

// Fused: forward col FFT -> epilogue (out write + masked residual)
//        -> inverse col FFT of residual, all in one LDS tile.
// buf rows are already row-FFT'd (G after this kernel's fwd stages).
//   if (write_out) outp[i] = base[i] - S*G/256
//   resid = mask[p] ? G/256 - S*ksp[i] : 0
//   buf <- IFFTu_cols(resid)            (natural order; rows-iFFT next)
// grid (64, NC), 256 thr.
__global__ __launch_bounds__(256) void fft_cols_fused(c32* __restrict__ buf,
        const c32* __restrict__ base, const c32* __restrict__ ksp,
        const int* __restrict__ mask, c32* __restrict__ outp, int write_out) {
    __shared__ c32 lds[4][257];
    __shared__ c32 tw[128];
    int tid = threadIdx.x;
    build_tw(tw, tid);
    int coil = blockIdx.y;
    c32* ip = buf + (size_t)coil * HW;
    int x0 = blockIdx.x * 4;
    int cl = tid & 3, yb = tid >> 2;
    #pragma unroll
    for (int e = 0; e < 4; ++e) {
        int y = yb + (e << 6);
        lds[cl][__brev((unsigned)y) >> 24] = ip[y * 256 + x0 + cl];
    }
    __syncthreads();
    int col = tid >> 6, j = tid & 63;
    fft256_stages(&lds[col][0], tw, j, 1.0f);   // ends with __syncthreads

    // epilogue: read all G first (registers), then sync, then write bit-rev resid
    int x = x0 + cl;
    c32 G[4];
    #pragma unroll
    for (int e = 0; e < 4; ++e) {
        int y = yb + (e << 6);
        G[e] = lds[cl][y];
    }
    __syncthreads();                            // all G reads done
    #pragma unroll
    for (int e = 0; e < 4; ++e) {
        int y = yb + (e << 6);
        int p = y * 256 + x;
        size_t i = (size_t)coil * HW + p;
        float s = ((p ^ (p >> 8)) & 1) ? -1.0f : 1.0f;
        if (write_out) {
            c32 bv = base[i];
            float sc = s * (1.0f / 256.0f);
            outp[i] = make_float2(bv.x - sc * G[e].x, bv.y - sc * G[e].y);
        }
        c32 rv = make_float2(0.f, 0.f);
        if (mask[p]) {
            c32 k = ksp[i];
            rv = make_float2(G[e].x * (1.0f / 256.0f) - s * k.x,
                             G[e].y * (1.0f / 256.0f) - s * k.y);
        }
        lds[cl][__brev((unsigned)y) >> 24] = rv;   // bit-rev input for inverse
    }
    __syncthreads();                            // all resid writes done
    fft256_stages(&lds[col][0], tw, j, -1.0f);
    #pragma unroll
    for (int e = 0; e < 4; ++e) {
        int y = yb + (e << 6);
        ip[y * 256 + x0 + cl] = lds[cl][y];
    }
}

// ===================== pointwise kernels =====================
__global__ __launch_bounds__(256) void k_combine_eta0(const c32* __restrict__ tmp,
        const c32* __restrict__ sense, c32* __restrict__ eta) {
    int p = blockIdx.x * 256 + threadIdx.x;
    float ax = 0.f, ay = 0.f;
    for (int c = 0; c < NC; ++c) {
        c32 t = tmp[c * HW + p], s = sense[c * HW + p];
        ax += t.x * s.x + t.y * s.y;
        ay += t.y * s.x - t.x * s.y;
    }
    float sc = ssign(p) * (1.0f / 256.0f);
    eta[p] = make_float2(ax * sc, ay * sc);
}

__global__ __launch_bounds__(256) void k_base(const c32* __restrict__ ksp,
        const c32* __restrict__ pred, const int* __restrict__ mask,
        const float* __restrict__ dcw, c32* __restrict__ base) {
    int i = blockIdx.x * 256 + threadIdx.x;
    int p = i & (HW - 1);
    c32 k = ksp[i];
    c32 o = k;
    if (mask[p]) {
        float w = dcw[0];
        c32 pr = pred[i];
        o.x -= (pr.x - k.x) * w;
        o.y -= (pr.y - k.y) * w;
    }
    base[i] = o;
}

// grad+g: emit conv1 input directly as transposed bf16 gT[px][4]
__global__ __launch_bounds__(256) void k_grad_g(const c32* __restrict__ tmp,
        const c32* __restrict__ sense, const c32* __restrict__ eta,
        short* __restrict__ gT) {
    int p = blockIdx.x * 256 + threadIdx.x;
    float ax = 0.f, ay = 0.f;
    for (int c = 0; c < NC; ++c) {
        c32 t = tmp[c * HW + p], s = sense[c * HW + p];
        ax += t.x * s.x + t.y * s.y;
        ay += t.y * s.x - t.x * s.y;
    }
    float sc = ssign(p) * (1.0f / 256.0f);
    c32 e = eta[p];
    ushort4 o;
    o.x = (unsigned short)f2bf(e.x);
    o.y = (unsigned short)f2bf(e.y);
    o.z = (unsigned short)f2bf(ax * sc);
    o.w = (unsigned short)f2bf(ay * sc);
    ((ushort4*)gT)[p] = o;
}

// ===================== weight prep kernels =====================
__global__ __launch_bounds__(256) void k_prep_c1(const float* __restrict__ w,
        short* __restrict__ wA) {
    int i = blockIdx.x * 256 + threadIdx.x;    // 64*128 = 8192
    int co = i >> 7, k = i & 127;
    int tap = k >> 2, ci = k & 3;
    float v = (tap < 25) ? w[co * 100 + ci * 25 + tap] : 0.f;
    wA[i] = f2bf(v);
}

__global__ __launch_bounds__(256) void k_prep_c2(const float* __restrict__ w,
        short* __restrict__ wA) {
    int i = blockIdx.x * 256 + threadIdx.x;     // 36864 total
    int tap = i >> 12, co = (i >> 6) & 63, ci = i & 63;
    wA[i] = f2bf(w[co * 576 + ci * 9 + tap]);
}

__global__ __launch_bounds__(256) void k_prep_cf(const float* __restrict__ w,
        short* __restrict__ wA) {
    int i = blockIdx.x * 256 + threadIdx.x;    // 9*16*64 = 9216
    int tap = i >> 10, r = (i >> 6) & 15, ci = i & 63;
    float v = (r < 2) ? w[r * 576 + ci * 9 + tap] : 0.f;
    wA[i] = f2bf(v);
}

__global__ __launch_bounds__(128) void k_prep_gru(const float* __restrict__ ihw,
        const float* __restrict__ ihb, const float* __restrict__ hhw,
        const float* __restrict__ hhb, short* __restrict__ w2, float* __restrict__ bias) {
    int k = threadIdx.x;      // 0..127
    int r = blockIdx.x;       // 0..255
    int g = r >> 6, co = r & 63;
    float v = 0.f;
    if (g == 0)      v = (k < 64) ? ihw[co * 64 + k]         : hhw[co * 64 + k - 64];
    else if (g == 1) v = (k < 64) ? ihw[(64 + co) * 64 + k]  : hhw[(64 + co) * 64 + k - 64];
    else if (g == 2) v = (k < 64) ? ihw[(128 + co) * 64 + k] : 0.f;
    else             v = (k < 64) ? 0.f : hhw[(128 + co) * 64 + k - 64];
    w2[r * 128 + k] = f2bf(v);
    if (k == 0) {
        float b = (g == 0) ? ihb[co] + hhb[co]
                : (g == 1) ? ihb[64 + co] + hhb[64 + co]
                : (g == 2) ? ihb[128 + co] : hhb[128 + co];
        bias[r] = b;
    }
}

// ===================== conv1 via MFMA =====================
__global__ __launch_bounds__(256, 2) void conv1_mfma(const short* __restrict__ gT,
        const short* __restrict__ wA, const float* __restrict__ bias,
        float* __restrict__ out) {
    int wv = threadIdx.x >> 6, l = threadIdx.x & 63;
    int lr = l & 15, lg = l >> 4;
    int y = blockIdx.x >> 2;
    int x0 = (blockIdx.x & 3) << 6;

    bf16x8 A[4];
    const short* pA = wA + (size_t)(wv * 16 + lr) * 128 + lg * 8;
    #pragma unroll
    for (int kt = 0; kt < 4; ++kt) A[kt] = *(const bf16x8*)(pA + kt * 32);

    f32x4 C[4];
    #pragma unroll
    for (int nt = 0; nt < 4; ++nt) {
        C[nt] = (f32x4){0.f, 0.f, 0.f, 0.f};
        int x = x0 + nt * 16 + lr;
        #pragma unroll
        for (int kt = 0; kt < 4; ++kt) {
            int t0 = kt * 8 + lg * 2;
            bf16x8 B;
            #pragma unroll
            for (int half = 0; half < 2; ++half) {
                int tap = t0 + half;
                int dy = tap / 5 - 2, dx = tap % 5 - 2;
                int yy = y + dy, xx = x + dx;
                bool ok = (tap < 25) && ((unsigned)yy < 256u) && ((unsigned)xx < 256u);
                ushort4 v = make_ushort4(0, 0, 0, 0);
                if (ok) v = *(const ushort4*)(gT + ((size_t)(yy * 256 + xx) << 2));
                B[half * 4 + 0] = (short)v.x;
                B[half * 4 + 1] = (short)v.y;
                B[half * 4 + 2] = (short)v.z;
                B[half * 4 + 3] = (short)v.w;
            }
            C[nt] = __builtin_amdgcn_mfma_f32_16x16x32_bf16(A[kt], B, C[nt], 0, 0, 0);
        }
    }
    int co = wv * 16 + lg * 4;
    #pragma unroll
    for (int nt = 0; nt < 4; ++nt) {
        int px = y * 256 + x0 + nt * 16 + lr;
        #pragma unroll
        for (int i = 0; i < 4; ++i)
            out[(size_t)(co + i) * HW + px] = fmaxf(C[nt][i] + bias[co + i], 0.f);
    }
}

// ===================== conv2 via MFMA =====================
__global__ __launch_bounds__(256, 2) void conv2_mfma(const short* __restrict__ hT,
        const short* __restrict__ wA, const float* __restrict__ bias,
        float* __restrict__ out) {
    int wv = threadIdx.x >> 6, l = threadIdx.x & 63;
    int lr = l & 15, lg = l >> 4;
    int y = blockIdx.x >> 2;
    int x0 = (blockIdx.x & 3) << 6;

    f32x4 C[4];
    #pragma unroll
    for (int nt = 0; nt < 4; ++nt) C[nt] = (f32x4){0.f, 0.f, 0.f, 0.f};

    #pragma unroll
    for (int tap = 0; tap < 9; ++tap) {
        const int dy = (tap / 3 - 1) * 2, dx = (tap % 3 - 1) * 2;
        int yy = y + dy;
        bool yok = (unsigned)yy < 256u;
        const short* pA = wA + (size_t)(tap * 64 + wv * 16 + lr) * 64 + lg * 8;
        bf16x8 A0 = *(const bf16x8*)(pA);
        bf16x8 A1 = *(const bf16x8*)(pA + 32);
        #pragma unroll
        for (int nt = 0; nt < 4; ++nt) {
            int xx = x0 + nt * 16 + lr + dx;
            bool ok = yok && ((unsigned)xx < 256u);
            int pcl = ok ? (yy * 256 + xx) : 0;
            const short* pB = hT + (size_t)pcl * 64 + lg * 8;
            bf16x8 B0 = {}, B1 = {};
            if (ok) {
                B0 = *(const bf16x8*)(pB);
                B1 = *(const bf16x8*)(pB + 32);
            }
            C[nt] = __builtin_amdgcn_mfma_f32_16x16x32_bf16(A0, B0, C[nt], 0, 0, 0);
            C[nt] = __builtin_amdgcn_mfma_f32_16x16x32_bf16(A1, B1, C[nt], 0, 0, 0);
        }
    }
    int co = wv * 16 + lg * 4;
    #pragma unroll
    for (int nt = 0; nt < 4; ++nt) {
        int px = y * 256 + x0 + nt * 16 + lr;
        #pragma unroll
        for (int i = 0; i < 4; ++i)
            out[(size_t)(co + i) * HW + px] = fmaxf(C[nt][i] + bias[co + i], 0.f);
    }
}

// ===================== GRU via MFMA =====================
__global__ __launch_bounds__(256, 2) void gru_mfma(const float* __restrict__ xin,
        const float* __restrict__ h, const short* __restrict__ w2,
        const float* __restrict__ bias, float* __restrict__ hout,
        short* __restrict__ hT) {
    int wv = threadIdx.x >> 6, l = threadIdx.x & 63;
    int lr = l & 15, lg = l >> 4;
    int px0 = blockIdx.x * 64;

    bf16x8 A0[4], A1[4], A2[2], A3[2];
    {
        const short* w0 = w2 + (0   + wv * 16 + lr) * 128 + lg * 8;
        const short* w1 = w2 + (64  + wv * 16 + lr) * 128 + lg * 8;
        const short* w2p = w2 + (128 + wv * 16 + lr) * 128 + lg * 8;
        const short* w3 = w2 + (192 + wv * 16 + lr) * 128 + lg * 8;
        #pragma unroll
        for (int kt = 0; kt < 4; ++kt) {
            A0[kt] = *(const bf16x8*)(w0 + kt * 32);
            A1[kt] = *(const bf16x8*)(w1 + kt * 32);
        }
        A2[0] = *(const bf16x8*)(w2p);          A2[1] = *(const bf16x8*)(w2p + 32);
        A3[0] = *(const bf16x8*)(w3 + 64);      A3[1] = *(const bf16x8*)(w3 + 96);
    }

    f32x4 C0[4], C1[4], C2[4], C3[4];
    #pragma unroll
    for (int nt = 0; nt < 4; ++nt) {
        C0[nt] = (f32x4){0.f, 0.f, 0.f, 0.f};
        C1[nt] = (f32x4){0.f, 0.f, 0.f, 0.f};
        C2[nt] = (f32x4){0.f, 0.f, 0.f, 0.f};
        C3[nt] = (f32x4){0.f, 0.f, 0.f, 0.f};
    }

    #pragma unroll
    for (int nt = 0; nt < 4; ++nt) {
        int px = px0 + nt * 16 + lr;
        bf16x8 B[4];
        #pragma unroll
        for (int kt = 0; kt < 4; ++kt) {
            const float* src = (kt < 2) ? xin + (size_t)(kt * 32 + lg * 8) * HW + px
                                        : h   + (size_t)((kt - 2) * 32 + lg * 8) * HW + px;
            #pragma unroll
            for (int j = 0; j < 8; ++j) B[kt][j] = f2bf(src[(size_t)j * HW]);
        }
        #pragma unroll
        for (int kt = 0; kt < 4; ++kt) {
            C0[nt] = __builtin_amdgcn_mfma_f32_16x16x32_bf16(A0[kt], B[kt], C0[nt], 0, 0, 0);
            C1[nt] = __builtin_amdgcn_mfma_f32_16x16x32_bf16(A1[kt], B[kt], C1[nt], 0, 0, 0);
        }
        C2[nt] = __builtin_amdgcn_mfma_f32_16x16x32_bf16(A2[0], B[0], C2[nt], 0, 0, 0);
        C2[nt] = __builtin_amdgcn_mfma_f32_16x16x32_bf16(A2[1], B[1], C2[nt], 0, 0, 0);
        C3[nt] = __builtin_amdgcn_mfma_f32_16x16x32_bf16(A3[0], B[2], C3[nt], 0, 0, 0);
        C3[nt] = __builtin_amdgcn_mfma_f32_16x16x32_bf16(A3[1], B[3], C3[nt], 0, 0, 0);
    }

    int co = wv * 16 + lg * 4;
    float br[4], bz[4], bin_[4], bhn[4];
    #pragma unroll
    for (int i = 0; i < 4; ++i) {
        br[i]   = bias[co + i];
        bz[i]   = bias[64 + co + i];
        bin_[i] = bias[128 + co + i];
        bhn[i]  = bias[192 + co + i];
    }
    #pragma unroll
    for (int nt = 0; nt < 4; ++nt) {
        int px = px0 + nt * 16 + lr;
        #pragma unroll
        for (int i = 0; i < 4; ++i) {
            float r = 1.0f / (1.0f + expf(-(C0[nt][i] + br[i])));
            float z = 1.0f / (1.0f + expf(-(C1[nt][i] + bz[i])));
            float nn = tanhf(C2[nt][i] + bin_[i] + r * (C3[nt][i] + bhn[i]));
            float ho = h[(size_t)(co + i) * HW + px];
            float hv = (1.0f - z) * nn + z * ho;
            hout[(size_t)(co + i) * HW + px] = hv;
            if (hT) hT[(size_t)px * 64 + co + i] = f2bf(hv);
        }
    }
}

// ===================== final conv via MFMA =====================
__global__ __launch_bounds__(256, 2) void final_mfma(const short* __restrict__ hT,
        const short* __restrict__ wA, c32* __restrict__ eta) {
    int wv = threadIdx.x >> 6, l = threadIdx.x & 63;
    int lr = l & 15, lg = l >> 4;
    int y = blockIdx.x >> 2;
    int x0 = (blockIdx.x & 3) << 6;
    int x = x0 + wv * 16 + lr;

    f32x4 C = (f32x4){0.f, 0.f, 0.f, 0.f};
    #pragma unroll
    for (int tap = 0; tap < 9; ++tap) {
        int dy = tap / 3 - 1, dx = tap % 3 - 1;
        int yy = y + dy, xx = x + dx;
        bool ok = ((unsigned)yy < 256u) && ((unsigned)xx < 256u);
        const short* pA = wA + (size_t)(tap * 16 + lr) * 64 + lg * 8;
        bf16x8 A0 = *(const bf16x8*)(pA);
        bf16x8 A1 = *(const bf16x8*)(pA + 32);
        int pcl = ok ? (yy * 256 + xx) : 0;
        const short* pB = hT + ((size_t)pcl << 6) + lg * 8;
        bf16x8 B0 = {}, B1 = {};
        if (ok) {
            B0 = *(const bf16x8*)(pB);
            B1 = *(const bf16x8*)(pB + 32);
        }
        C = __builtin_amdgcn_mfma_f32_16x16x32_bf16(A0, B0, C, 0, 0, 0);
        C = __builtin_amdgcn_mfma_f32_16x16x32_bf16(A1, B1, C, 0, 0, 0);
    }
    if (lg == 0) {
        int px = y * 256 + x;
        c32 e = eta[px];
        eta[px] = make_float2(e.x + C[0], e.y + C[1]);
    }
}

// ===================== host orchestration =====================
extern "C" void kernel_launch(void* const* d_in, const int* in_sizes, int n_in,
                              void* d_out, int out_size, void* d_ws, size_t ws_size,
                              hipStream_t stream) {
    const c32* pred   = (const c32*)d_in[0];
    const c32* ksp    = (const c32*)d_in[1];
    const c32* sense  = (const c32*)d_in[2];
    const int* mask   = (const int*)d_in[3];
    const float* c1w  = (const float*)d_in[4];
    const float* c1b  = (const float*)d_in[5];
    const float* g1iw = (const float*)d_in[6];
    const float* g1ib = (const float*)d_in[7];
    const float* g1hw = (const float*)d_in[8];
    const float* g1hb = (const float*)d_in[9];
    const float* c2w  = (const float*)d_in[10];
    const float* c2b  = (const float*)d_in[11];
    const float* g2iw = (const float*)d_in[12];
    const float* g2ib = (const float*)d_in[13];
    const float* g2hw = (const float*)d_in[14];
    const float* g2hb = (const float*)d_in[15];
    const float* fw   = (const float*)d_in[16];
    const float* dcw  = (const float*)d_in[17];

    float* w0 = (float*)d_ws;
    c32* base = (c32*)w0;                  // NC*HW complex
    c32* Fk   = base + NC * HW;            // NC*HW complex
    c32* tmp  = Fk + NC * HW;              // NC*HW complex (init only)
    c32* eta  = tmp + NC * HW;             // HW complex
    short* gT = (short*)(eta + HW);        // HW*4 bf16
    float* x1 = (float*)(gT + (size_t)HW * 4);  // NF*HW
    float* h1a = x1 + NF * HW;
    float* h1b = h1a + NF * HW;
    float* h2a = h1b + NF * HW;
    float* h2b = h2a + NF * HW;
    short* w2a  = (short*)(h2b + NF * HW); // 256*128 bf16
    short* w2b  = w2a + 256 * 128;
    float* biasA = (float*)(w2b + 256 * 128);
    float* biasB = biasA + 256;
    short* h1T  = (short*)(biasB + 256);   // HW*64 bf16
    short* h2T  = h1T + (size_t)HW * 64;   // HW*64 bf16
    short* wAc2 = h2T + (size_t)HW * 64;   // 9*64*64 bf16
    short* wAc1 = wAc2 + 9 * 64 * 64;      // 64*128 bf16
    short* wAcf = wAc1 + 64 * 128;         // 9*16*64 bf16

    (void)hipMemsetAsync(h1a, 0, (size_t)NF * HW * 4, stream);
    (void)hipMemsetAsync(h2a, 0, (size_t)NF * HW * 4, stream);

    dim3 B(256);
    const int gCHW = NC * HW / 256;   // 3072
    const int gHW  = HW / 256;        // 256
    const int gROW = NC * 256 / 4;    // 768
    dim3 gCOL(64, NC);
    const int gGRU = HW / 64;         // 1024 blocks

    // weight prep (once per call)
    k_prep_gru<<<256, 128, 0, stream>>>(g1iw, g1ib, g1hw, g1hb, w2a, biasA);
    k_prep_gru<<<256, 128, 0, stream>>>(g2iw, g2ib, g2hw, g2hb, w2b, biasB);
    k_prep_c2<<<144, 256, 0, stream>>>(c2w, wAc2);
    k_prep_c1<<<32, 256, 0, stream>>>(c1w, wAc1);
    k_prep_cf<<<36, 256, 0, stream>>>(fw, wAcf);

    // eta0 = sum_c ifft2c(pred_c) * conj(sense_c)
    fft_rows_pre<<<gROW, B, 0, stream>>>(tmp, pred);
    fft_cols<<<gCOL, B, 0, stream>>>(tmp, -1.0f);
    k_combine_eta0<<<gHW, B, 0, stream>>>(tmp, sense, eta);

    k_base<<<gCHW, B, 0, stream>>>(ksp, pred, mask, dcw, base);

    // F_0: forward FFT of S*(eta0*sense); fused epilogue leaves col-iFFT'd
    // residual in Fk (no out write).
    fft_rows_exp<<<gROW, B, 0, stream>>>(Fk, eta, sense);
    fft_cols_fused<<<gCOL, B, 0, stream>>>(Fk, base, ksp, mask, (c32*)d_out, 0);

    float* h1c = h1a; float* h1n = h1b;
    float* h2c = h2a; float* h2n = h2b;
    c32* outp = (c32*)d_out;

    for (int t = 0; t < NT; ++t) {
        // complete iFFT of residual (rows), then gradient + g
        fft_rows<<<gROW, B, 0, stream>>>(Fk, -1.0f);
        k_grad_g<<<gHW, B, 0, stream>>>(Fk, sense, eta, gT);

        // network (all MFMA)
        conv1_mfma<<<gGRU, B, 0, stream>>>(gT, wAc1, c1b, x1);
        gru_mfma<<<gGRU, B, 0, stream>>>(x1, h1c, w2a, biasA, h1n, h1T);
        { float* s = h1c; h1c = h1n; h1n = s; }
        conv2_mfma<<<gGRU, B, 0, stream>>>(h1T, wAc2, c2b, x1);
        gru_mfma<<<gGRU, B, 0, stream>>>(x1, h2c, w2b, biasB, h2n, h2T);
        { float* s = h2c; h2c = h2n; h2n = s; }
        final_mfma<<<gGRU, B, 0, stream>>>(h2T, wAcf, eta);

        // F_t: forward rows (fused expand), fused cols -> out[t] + next residual
        fft_rows_exp<<<gROW, B, 0, stream>>>(Fk, eta, sense);
        fft_cols_fused<<<gCOL, B, 0, stream>>>(Fk, base, ksp, mask,
                                               outp + (size_t)t * NC * HW, 1);
    }
}